// Round 1
// baseline (1863.558 us; speedup 1.0000x reference)
//
#include <hip/hip_runtime.h>
#include <math.h>

// ---------------------------------------------------------------------------
// Net: 4x (conv3x3 + batchnorm(batch-stats) + relu(maxpool2)) -> offset conv
//      -> deformable conv -> relu -> bn5 -> spatial mean -> fc -> log_softmax
// B=128, HW=64, C=64, fp32 everywhere (round 1: correctness-first baseline)
// ---------------------------------------------------------------------------

// ======================= generic 3x3 pad-1 conv ============================
// MODE 0: store conv out + per-channel sum/sumsq atomics (BN stats)
// MODE 1: stats only (no store)          -- used for conv1 pass A
// MODE 2: apply BN affine + relu + 2x2 maxpool, store pooled -- conv1 pass B
template<int CIN, int H, int W, int TH, int TW, int P, int COPB, int COUT, int MODE>
__global__ __launch_bounds__(256)
void conv3x3_kernel(const float* __restrict__ in, const float* __restrict__ wgt,
                    const float* __restrict__ bias, float* __restrict__ out,
                    float* __restrict__ stat_sum, float* __restrict__ stat_sq,
                    const float* __restrict__ bnA, const float* __restrict__ bnB)
{
    constexpr int TB = (H / TH) * (W / TW);
    constexpr int QX = TW / 2, QY = TH / 2;
    constexpr int SH = TH + 2, SW = TW + 2;
    constexpr int SLAB = P * SH * SW;
    __shared__ float slab[P][SH][SW];
    __shared__ float redbuf[4 * COPB * 2];

    const int tid   = threadIdx.x;
    const int bg    = blockIdx.x / TB;
    const int tile  = blockIdx.x % TB;
    const int ty    = (tile / (W / TW)) * TH;
    const int tx    = (tile % (W / TW)) * TW;
    const int b0    = bg * P;
    const int cout0 = blockIdx.y * COPB;

    const int p  = tid / (QY * QX);
    const int q  = tid % (QY * QX);
    const int qy = q / QX, qx = q % QX;
    const int oy = ty + 2 * qy, ox = tx + 2 * qx;

    float acc[4][COPB];
#pragma unroll
    for (int i = 0; i < 4; i++)
#pragma unroll
        for (int oc = 0; oc < COPB; oc++) acc[i][oc] = bias[cout0 + oc];

#pragma unroll 1
    for (int cin = 0; cin < CIN; ++cin) {
        __syncthreads();
        for (int idx = tid; idx < SLAB; idx += 256) {
            int pp = idx / (SH * SW); int r = idx - pp * (SH * SW);
            int sy = r / SW, sx = r - sy * SW;
            int gy = ty + sy - 1, gx = tx + sx - 1;
            float v = 0.f;
            if (gy >= 0 && gy < H && gx >= 0 && gx < W)
                v = in[(((size_t)(b0 + pp) * CIN + cin) * H + gy) * W + gx];
            (&slab[0][0][0])[idx] = v;
        }
        __syncthreads();
        float v[4][4];
#pragma unroll
        for (int r = 0; r < 4; r++) {
            float2 a = *(const float2*)&slab[p][2 * qy + r][2 * qx];
            float2 b = *(const float2*)&slab[p][2 * qy + r][2 * qx + 2];
            v[r][0] = a.x; v[r][1] = a.y; v[r][2] = b.x; v[r][3] = b.y;
        }
        const float* wp = wgt + ((size_t)cout0 * CIN + cin) * 9;
#pragma unroll
        for (int oc = 0; oc < COPB; oc++) {
            const float* w9 = wp + (size_t)oc * CIN * 9;
            float w0 = w9[0], w1 = w9[1], w2 = w9[2], w3 = w9[3], w4 = w9[4],
                  w5 = w9[5], w6 = w9[6], w7 = w9[7], w8 = w9[8];
#pragma unroll
            for (int dy = 0; dy < 2; dy++)
#pragma unroll
                for (int dx = 0; dx < 2; dx++) {
                    float s = w0 * v[dy][dx];
                    s = fmaf(w1, v[dy][dx + 1], s);
                    s = fmaf(w2, v[dy][dx + 2], s);
                    s = fmaf(w3, v[dy + 1][dx], s);
                    s = fmaf(w4, v[dy + 1][dx + 1], s);
                    s = fmaf(w5, v[dy + 1][dx + 2], s);
                    s = fmaf(w6, v[dy + 2][dx], s);
                    s = fmaf(w7, v[dy + 2][dx + 1], s);
                    s = fmaf(w8, v[dy + 2][dx + 2], s);
                    acc[dy * 2 + dx][oc] += s;
                }
        }
    }

    if constexpr (MODE == 0) {
#pragma unroll
        for (int oc = 0; oc < COPB; oc++) {
            size_t base = (((size_t)(b0 + p) * COUT + cout0 + oc) * H + oy) * W + ox;
            *(float2*)&out[base]     = make_float2(acc[0][oc], acc[1][oc]);
            *(float2*)&out[base + W] = make_float2(acc[2][oc], acc[3][oc]);
        }
    }
    if constexpr (MODE == 0 || MODE == 1) {
        float ps[COPB], pq[COPB];
#pragma unroll
        for (int oc = 0; oc < COPB; oc++) {
            float s = acc[0][oc] + acc[1][oc] + acc[2][oc] + acc[3][oc];
            float q2 = acc[0][oc] * acc[0][oc] + acc[1][oc] * acc[1][oc] +
                       acc[2][oc] * acc[2][oc] + acc[3][oc] * acc[3][oc];
#pragma unroll
            for (int off = 32; off > 0; off >>= 1) {
                s  += __shfl_down(s, off);
                q2 += __shfl_down(q2, off);
            }
            ps[oc] = s; pq[oc] = q2;
        }
        int wave = tid >> 6, lane = tid & 63;
        if (lane == 0) {
#pragma unroll
            for (int oc = 0; oc < COPB; oc++) {
                redbuf[(wave * COPB + oc) * 2 + 0] = ps[oc];
                redbuf[(wave * COPB + oc) * 2 + 1] = pq[oc];
            }
        }
        __syncthreads();
        if (tid < COPB) {
            float s  = 0.f, q2 = 0.f;
#pragma unroll
            for (int w = 0; w < 4; w++) {
                s  += redbuf[(w * COPB + tid) * 2 + 0];
                q2 += redbuf[(w * COPB + tid) * 2 + 1];
            }
            atomicAdd(&stat_sum[cout0 + tid], s);
            atomicAdd(&stat_sq[cout0 + tid], q2);
        }
    }
    if constexpr (MODE == 2) {
#pragma unroll
        for (int oc = 0; oc < COPB; oc++) {
            float Av = bnA[cout0 + oc], Bv = bnB[cout0 + oc];
            float m0 = fmaxf(fmaf(acc[0][oc], Av, Bv), fmaf(acc[1][oc], Av, Bv));
            float m1 = fmaxf(fmaf(acc[2][oc], Av, Bv), fmaf(acc[3][oc], Av, Bv));
            float m  = fmaxf(fmaxf(m0, m1), 0.f);
            out[(((size_t)(b0 + p) * COUT + cout0 + oc) * (H / 2) + (oy >> 1)) * (W / 2) + (ox >> 1)] = m;
        }
    }
}

// ================= BN finalize: A=g*rsqrt(var+eps), B=b-mu*A ===============
__global__ void bn_finalize(const float* __restrict__ sum, const float* __restrict__ sq,
                            const float* __restrict__ g, const float* __restrict__ b,
                            float* __restrict__ A, float* __restrict__ Bc,
                            int C, float invN)
{
    int c = threadIdx.x;
    if (c < C) {
        float mu  = sum[c] * invN;
        float var = sq[c] * invN - mu * mu;
        float s   = rsqrtf(var + 1e-5f) * g[c];
        A[c]  = s;
        Bc[c] = b[c] - mu * s;
    }
}

// ============ BN affine + relu + 2x2 maxpool (elementwise) =================
__global__ __launch_bounds__(256)
void bnpool_kernel(const float* __restrict__ in, const float* __restrict__ A,
                   const float* __restrict__ Bc, float* __restrict__ out,
                   int C, int Hh, int Wh, int total)
{
    int pw = Wh >> 1, ph = Hh >> 1;
    for (int i = blockIdx.x * 256 + threadIdx.x; i < total; i += gridDim.x * 256) {
        int x  = i % pw;
        int y  = (i / pw) % ph;
        int bc = i / (pw * ph);
        int c  = bc % C;
        const float* base = in + (size_t)bc * Hh * Wh;
        float2 a  = *(const float2*)&base[(2 * y) * Wh + 2 * x];
        float2 b2 = *(const float2*)&base[(2 * y + 1) * Wh + 2 * x];
        float Av = A[c], Bv = Bc[c];
        float m = fmaxf(fmaxf(fmaf(a.x, Av, Bv), fmaf(a.y, Av, Bv)),
                        fmaxf(fmaf(b2.x, Av, Bv), fmaf(b2.y, Av, Bv)));
        out[i] = fmaxf(m, 0.f);
    }
}

// =============== offset conv: 256 -> 18 channels at 4x4 ====================
__global__ __launch_bounds__(256)
void offconv_kernel(const float* __restrict__ h, const float* __restrict__ ow,
                    const float* __restrict__ ob, float* __restrict__ off)
{
    __shared__ float plane[256][36]; // zero-padded 6x6 per channel
    int b = blockIdx.x, tid = threadIdx.x;
    for (int i = tid; i < 256 * 36; i += 256) (&plane[0][0])[i] = 0.f;
    __syncthreads();
    for (int i = tid; i < 4096; i += 256) {
        int c = i >> 4, px = i & 15;
        plane[c][((px >> 2) + 1) * 6 + (px & 3) + 1] = h[((size_t)b * 256 + c) * 16 + px];
    }
    __syncthreads();
    for (int o = tid; o < 288; o += 256) {
        int co = o >> 4, px = o & 15, y = px >> 2, x = px & 3;
        float s = ob[co];
        const float* wb = ow + (size_t)co * 256 * 9;
        for (int c = 0; c < 256; c++) {
            const float* wc = wb + c * 9;
            const float* pl = &plane[c][y * 6 + x];
#pragma unroll
            for (int r = 0; r < 3; r++)
#pragma unroll
                for (int k = 0; k < 3; k++)
                    s = fmaf(wc[r * 3 + k], pl[r * 6 + k], s);
        }
        off[((size_t)b * 18 + co) * 16 + px] = s;
    }
}

// ============ deformable sampling: build xo[b*16+px][c*9+n] ================
__global__ __launch_bounds__(256)
void sample_kernel(const float* __restrict__ h, const float* __restrict__ off,
                   float* __restrict__ xo)
{
    __shared__ float plane[256][36];
    __shared__ int   tidx[144][4];
    __shared__ float twt[144][4];
    int b = blockIdx.x, tid = threadIdx.x;
    for (int i = tid; i < 256 * 36; i += 256) (&plane[0][0])[i] = 0.f;
    __syncthreads();
    for (int i = tid; i < 4096; i += 256) {
        int c = i >> 4, px = i & 15;
        plane[c][((px >> 2) + 1) * 6 + (px & 3) + 1] = h[((size_t)b * 256 + c) * 16 + px];
    }
    if (tid < 144) {
        int px = tid / 9, n = tid % 9;
        int y = px >> 2, x = px & 3;
        float ox_ = off[((size_t)b * 18 + 2 * n) * 16 + px];
        float oy_ = off[((size_t)b * 18 + 2 * n + 1) * 16 + px];
        float pxc = (float)(y + 1) + (float)(n / 3 - 1) + ox_;
        float pyc = (float)(x + 1) + (float)(n % 3 - 1) + oy_;
        if (pxc < 1.f || pxc > 4.f) pxc = floorf(pxc);
        if (pyc < 1.f || pyc > 4.f) pyc = floorf(pyc);
        pxc = fminf(fmaxf(pxc, 0.f), 5.f);
        pyc = fminf(fmaxf(pyc, 0.f), 5.f);
        float fx = floorf(pxc), fy = floorf(pyc);
        float qrbx = fminf(fx + 1.f, 5.f), qrby = fminf(fy + 1.f, 5.f);
        float wx_lt = 1.f + (fx - pxc),   wx_rb = 1.f - (qrbx - pxc);
        float wy_lt = 1.f + (fy - pyc),   wy_rb = 1.f - (qrby - pyc);
        tidx[tid][0] = (int)(fx * 6.f + fy);     twt[tid][0] = wx_lt * wy_lt;
        tidx[tid][1] = (int)(qrbx * 6.f + qrby); twt[tid][1] = wx_rb * wy_rb;
        tidx[tid][2] = (int)(fx * 6.f + qrby);   twt[tid][2] = wx_lt * wy_rb;
        tidx[tid][3] = (int)(qrbx * 6.f + fy);   twt[tid][3] = wx_rb * wy_lt;
    }
    __syncthreads();
    for (int s = tid; s < 36864; s += 256) {
        int px = s / 2304, k = s - px * 2304;
        int c = k / 9, n = k - c * 9;
        int t = px * 9 + n;
        const float* pc = plane[c];
        float v = twt[t][0] * pc[tidx[t][0]] + twt[t][1] * pc[tidx[t][1]] +
                  twt[t][2] * pc[tidx[t][2]] + twt[t][3] * pc[tidx[t][3]];
        xo[((size_t)b * 16 + px) * 2304 + k] = v;
    }
}

// ====== deform GEMM: out[2048][256] += A[2048][2304] * W[256][2304]^T ======
// BM=32, BN=256, BK=32, K split in 4 (atomic accumulate). relu on read later.
__global__ __launch_bounds__(256)
void dconv_gemm(const float* __restrict__ A, const float* __restrict__ Bw,
                float* __restrict__ out)
{
    __shared__ float At[32][36];
    __shared__ float Bt[32][260];
    int tid = threadIdx.x;
    int m0  = blockIdx.x * 32;
    int k0  = blockIdx.y * 576;
    float acc[4][8] = {};
    int r0 = 4 * (tid >> 5);
    int n0 = 8 * (tid & 31);
#pragma unroll 1
    for (int kc = 0; kc < 576; kc += 32) {
        __syncthreads();
        for (int i = tid; i < 1024; i += 256) {
            int j = i & 31, r = i >> 5;
            At[j][r] = A[(size_t)(m0 + r) * 2304 + k0 + kc + j];
        }
        for (int i = tid; i < 8192; i += 256) {
            int j = i & 31, nn = i >> 5;
            Bt[j][nn] = Bw[(size_t)nn * 2304 + k0 + kc + j];
        }
        __syncthreads();
#pragma unroll
        for (int k = 0; k < 32; k++) {
            float4 a   = *(const float4*)&At[k][r0];
            float4 b0v = *(const float4*)&Bt[k][n0];
            float4 b1v = *(const float4*)&Bt[k][n0 + 4];
            float av[4] = {a.x, a.y, a.z, a.w};
            float bv[8] = {b0v.x, b0v.y, b0v.z, b0v.w, b1v.x, b1v.y, b1v.z, b1v.w};
#pragma unroll
            for (int i = 0; i < 4; i++)
#pragma unroll
                for (int j = 0; j < 8; j++)
                    acc[i][j] = fmaf(av[i], bv[j], acc[i][j]);
        }
    }
#pragma unroll
    for (int i = 0; i < 4; i++)
#pragma unroll
        for (int j = 0; j < 8; j++)
            atomicAdd(&out[(size_t)(m0 + r0 + i) * 256 + n0 + j], acc[i][j]);
}

// ============== bn5 stats over relu(dout): per-channel =====================
__global__ __launch_bounds__(256)
void stats5_kernel(const float* __restrict__ dout, float* __restrict__ sum5,
                   float* __restrict__ sq5)
{
    __shared__ float rs[256], rq[256];
    int c = blockIdx.x, tid = threadIdx.x;
    float s = 0.f, q = 0.f;
    for (int i = tid; i < 2048; i += 256) {
        float v = fmaxf(dout[(size_t)i * 256 + c], 0.f);
        s += v; q += v * v;
    }
    rs[tid] = s; rq[tid] = q; __syncthreads();
    for (int st = 128; st > 0; st >>= 1) {
        if (tid < st) { rs[tid] += rs[tid + st]; rq[tid] += rq[tid + st]; }
        __syncthreads();
    }
    if (tid == 0) { sum5[c] = rs[0]; sq5[c] = rq[0]; }
}

// ====== head: relu -> bn5-affine folded into mean -> fc -> log_softmax =====
__global__ __launch_bounds__(256)
void final_kernel(const float* __restrict__ dout, const float* __restrict__ A5,
                  const float* __restrict__ B5, const float* __restrict__ fcw,
                  const float* __restrict__ fcb, float* __restrict__ out)
{
    __shared__ float hbar[256];
    __shared__ float red[256];
    int b = blockIdx.x, tid = threadIdx.x;
    float s = 0.f;
#pragma unroll 4
    for (int px = 0; px < 16; px++)
        s += fmaxf(dout[((size_t)b * 16 + px) * 256 + tid], 0.f);
    hbar[tid] = fmaf(A5[tid], s * (1.f / 16.f), B5[tid]);
    __syncthreads();
    float logit = -1e30f;
    if (tid < 250) {
        float acc = fcb[tid];
        const float4* wr = (const float4*)(fcw + (size_t)tid * 256);
        const float4* hv = (const float4*)hbar;
#pragma unroll 4
        for (int i = 0; i < 64; i++) {
            float4 w4 = wr[i], h4 = hv[i];
            acc = fmaf(w4.x, h4.x, acc); acc = fmaf(w4.y, h4.y, acc);
            acc = fmaf(w4.z, h4.z, acc); acc = fmaf(w4.w, h4.w, acc);
        }
        logit = acc;
    }
    red[tid] = logit; __syncthreads();
    for (int st = 128; st > 0; st >>= 1) {
        if (tid < st) red[tid] = fmaxf(red[tid], red[tid + st]);
        __syncthreads();
    }
    float mx = red[0]; __syncthreads();
    float e = (tid < 250) ? expf(logit - mx) : 0.f;
    red[tid] = e; __syncthreads();
    for (int st = 128; st > 0; st >>= 1) {
        if (tid < st) red[tid] += red[tid + st];
        __syncthreads();
    }
    float lse = logf(red[0]) + mx;
    if (tid < 250) out[(size_t)b * 250 + tid] = logit - lse;
}

// ===========================================================================
extern "C" void kernel_launch(void* const* d_in, const int* in_sizes, int n_in,
                              void* d_out, int out_size, void* d_ws, size_t ws_size,
                              hipStream_t stream)
{
    const float* s_in = (const float*)d_in[0];
    const float* c1w = (const float*)d_in[1];  const float* c1b = (const float*)d_in[2];
    const float* g1  = (const float*)d_in[3];  const float* b1  = (const float*)d_in[4];
    const float* c2w = (const float*)d_in[5];  const float* c2b = (const float*)d_in[6];
    const float* g2  = (const float*)d_in[7];  const float* b2  = (const float*)d_in[8];
    const float* c3w = (const float*)d_in[9];  const float* c3b = (const float*)d_in[10];
    const float* g3  = (const float*)d_in[11]; const float* b3  = (const float*)d_in[12];
    const float* c4w = (const float*)d_in[13]; const float* c4b = (const float*)d_in[14];
    const float* g4  = (const float*)d_in[15]; const float* b4  = (const float*)d_in[16];
    const float* ofw = (const float*)d_in[17]; const float* ofb = (const float*)d_in[18];
    const float* dcw = (const float*)d_in[19];
    const float* g5  = (const float*)d_in[20]; const float* b5  = (const float*)d_in[21];
    const float* fcw = (const float*)d_in[22]; const float* fcb = (const float*)d_in[23];

    float* ws    = (float*)d_ws;
    float* stat  = ws;                       // 5 stages x (sum[256], sq[256]) = 2560
    float* ab    = ws + 2560;                // 5 stages x (A[256], B[256])    = 2560
    float* poolB = ws + 5120;                // 8,388,608 floats (reused by all stages)
    float* convB = poolB + 8388608;          // 16,777,216 floats (conv outs; then xo/dout/off)
    float* xo    = convB;                    // 4,718,592
    float* dout  = convB + 4718592;          // 524,288
    float* offb  = dout + 524288;            // 36,864

    // zero BN-stat accumulators for stages 1-4 (stage 5 written directly)
    hipMemsetAsync(stat, 0, 2048 * sizeof(float), stream);

    // ---- stage 1: conv1 (1->64, 64x64), recompute trick ----
    conv3x3_kernel<1, 64, 64, 32, 32, 1, 8, 64, 1><<<dim3(512, 8), 256, 0, stream>>>(
        s_in, c1w, c1b, nullptr, stat, stat + 256, nullptr, nullptr);
    bn_finalize<<<1, 256, 0, stream>>>(stat, stat + 256, g1, b1, ab, ab + 256, 64,
                                       1.0f / (128.f * 64.f * 64.f));
    conv3x3_kernel<1, 64, 64, 32, 32, 1, 8, 64, 2><<<dim3(512, 8), 256, 0, stream>>>(
        s_in, c1w, c1b, poolB, nullptr, nullptr, ab, ab + 256);

    // ---- stage 2: conv2 (64->128, 32x32) ----
    conv3x3_kernel<64, 32, 32, 32, 32, 1, 8, 128, 0><<<dim3(128, 16), 256, 0, stream>>>(
        poolB, c2w, c2b, convB, stat + 512, stat + 768, nullptr, nullptr);
    bn_finalize<<<1, 256, 0, stream>>>(stat + 512, stat + 768, g2, b2, ab + 512, ab + 768,
                                       128, 1.0f / (128.f * 32.f * 32.f));
    bnpool_kernel<<<2048, 256, 0, stream>>>(convB, ab + 512, ab + 768, poolB,
                                            128, 32, 32, 128 * 128 * 16 * 16);

    // ---- stage 3: conv3 (128->256, 16x16) ----
    conv3x3_kernel<128, 16, 16, 16, 16, 4, 8, 256, 0><<<dim3(32, 32), 256, 0, stream>>>(
        poolB, c3w, c3b, convB, stat + 1024, stat + 1280, nullptr, nullptr);
    bn_finalize<<<1, 256, 0, stream>>>(stat + 1024, stat + 1280, g3, b3, ab + 1024, ab + 1280,
                                       256, 1.0f / (128.f * 16.f * 16.f));
    bnpool_kernel<<<2048, 256, 0, stream>>>(convB, ab + 1024, ab + 1280, poolB,
                                            256, 16, 16, 128 * 256 * 8 * 8);

    // ---- stage 4: conv4 (256->256, 8x8) ----
    conv3x3_kernel<256, 8, 8, 8, 8, 16, 4, 256, 0><<<dim3(8, 64), 256, 0, stream>>>(
        poolB, c4w, c4b, convB, stat + 1536, stat + 1792, nullptr, nullptr);
    bn_finalize<<<1, 256, 0, stream>>>(stat + 1536, stat + 1792, g4, b4, ab + 1536, ab + 1792,
                                       256, 1.0f / (128.f * 8.f * 8.f));
    bnpool_kernel<<<2048, 256, 0, stream>>>(convB, ab + 1536, ab + 1792, poolB,
                                            256, 8, 8, 128 * 256 * 4 * 4);

    // ---- deformable conv ----
    offconv_kernel<<<128, 256, 0, stream>>>(poolB, ofw, ofb, offb);
    sample_kernel<<<128, 256, 0, stream>>>(poolB, offb, xo);
    hipMemsetAsync(dout, 0, 524288 * sizeof(float), stream);
    dconv_gemm<<<dim3(64, 4), 256, 0, stream>>>(xo, dcw, dout);

    // ---- bn5 + head ----
    stats5_kernel<<<256, 256, 0, stream>>>(dout, stat + 2048, stat + 2304);
    bn_finalize<<<1, 256, 0, stream>>>(stat + 2048, stat + 2304, g5, b5, ab + 2048, ab + 2304,
                                       256, 1.0f / 2048.f);
    final_kernel<<<128, 256, 0, stream>>>(dout, ab + 2048, ab + 2304, fcw, fcb, (float*)d_out);
}

// Round 3
// 692.677 us; speedup vs baseline: 2.6904x; 2.6904x over previous
//
#include <hip/hip_runtime.h>
#include <math.h>

typedef float  f32x4 __attribute__((ext_vector_type(4)));
typedef short  s16x8 __attribute__((ext_vector_type(8)));

__device__ __forceinline__ float b2f(ushort u) { return __uint_as_float(((unsigned)u) << 16); }
__device__ __forceinline__ ushort f2b(float f) {
    unsigned u = __float_as_uint(f);
    return (ushort)((u + 0x7FFFu + ((u >> 16) & 1u)) >> 16);
}
__device__ __forceinline__ void gload16(const void* g, void* l) {
    __builtin_amdgcn_global_load_lds((const __attribute__((address_space(1))) void*)g,
                                     (__attribute__((address_space(3))) void*)l, 16, 0, 0);
}

// ====== weight convert: fp32 OIHW -> bf16 hi/lo planes [CO][ksp*CI+ci] =====
__global__ __launch_bounds__(256)
void wcvt_kernel(const float* __restrict__ src, ushort* __restrict__ dsth,
                 ushort* __restrict__ dstl, int CI, int reorder, int total)
{
    int i = blockIdx.x * 256 + threadIdx.x;
    if (i >= total) return;
    float v;
    if (reorder) {
        int k9 = CI * 9;
        int co = i / k9; int rem = i - co * k9;
        int ksp = rem / CI; int ci = rem - ksp * CI;
        v = src[(size_t)(co * CI + ci) * 9 + ksp];
    } else {
        v = src[i];
    }
    ushort h = f2b(v);
    dsth[i] = h;
    dstl[i] = f2b(v - b2f(h));
}

// ================= split-bf16 MFMA implicit-GEMM ===========================
// out[M][COUT] (fp32) = A[M][K] * W[COUT][K]^T (+bias); A,W given as hi/lo
// bf16 planes; acc += ah*wh + al*wh + ah*wl  (error ~2^-18).
// BM=128, BN=64, BK=64; 4 waves (2x2), wave tile 64x32, 16x16x32 MFMA.
template<int KTOT, int CIN, int HH, int WW, int COUT, bool IM2COL, bool BIAS, bool STATS>
__global__ __launch_bounds__(256)
void gemm_kernel(const ushort* __restrict__ inH, const ushort* __restrict__ inL,
                 const ushort* __restrict__ wbh, const ushort* __restrict__ wbl,
                 const float* __restrict__ bias, float* __restrict__ out,
                 const ushort* __restrict__ zsrc0,
                 float* __restrict__ gsum, float* __restrict__ gsq)
{
    __shared__ union {
        struct { char ah[16384]; char al[16384]; char bh[8192]; char bl[8192]; } s;
        float c[128][66];
    } u;
    __shared__ float blkstat[64][2];

    const int tid  = threadIdx.x;
    const int lane = tid & 63, wv = tid >> 6;
    const int lr = lane & 15, lg = lane >> 4;
    const int wm = wv >> 1,  wn = wv & 1;
    const int m0 = blockIdx.x * 128;
    const int n0 = blockIdx.y * 64;
    const int sl = (lane & 7) ^ (lane >> 3);   // pre-swizzled source chunk

    int apix[4], ay[4] = {0,0,0,0}, ax[4] = {0,0,0,0};
#pragma unroll
    for (int g = 0; g < 4; g++) {
        int row = (wv * 4 + g) * 8 + (lane >> 3);
        int m = m0 + row;
        apix[g] = m;
        if constexpr (IM2COL) {
            int rem = m & (HH * WW - 1);
            ay[g] = rem / WW;
            ax[g] = rem & (WW - 1);
        }
    }
    size_t boff[2];
#pragma unroll
    for (int j2 = 0; j2 < 2; j2++) {
        int brow = (wv * 2 + j2) * 8 + (lane >> 3);
        boff[j2] = (size_t)(n0 + brow) * KTOT + sl * 8;
    }
    const ushort* zsrc = zsrc0 + sl * 8;

    float bv[2] = {0.f, 0.f};
    if (BIAS) { bv[0] = bias[n0 + wn * 32 + lr]; bv[1] = bias[n0 + wn * 32 + 16 + lr]; }

    f32x4 acc[4][2] = {};

    constexpr int NK = KTOT / 64;
#pragma unroll 1
    for (int kt = 0; kt < NK; kt++) {
        if constexpr (IM2COL) {
            int ksp = (kt * 64) / CIN;
            int c0  = (kt * 64) & (CIN - 1);
            int d3  = ksp / 3;
            int dy = d3 - 1, dx = ksp - d3 * 3 - 1;
            int dpix = dy * WW + dx;
#pragma unroll
            for (int g = 0; g < 4; g++) {
                int iy = ay[g] + dy, ix = ax[g] + dx;
                bool ok = ((unsigned)iy < (unsigned)HH && (unsigned)ix < (unsigned)WW);
                size_t so = (size_t)(apix[g] + dpix) * CIN + c0 + sl * 8;
                const ushort* sh = ok ? inH + so : zsrc;
                const ushort* sl_ = ok ? inL + so : zsrc;
                gload16(sh,  u.s.ah + (wv * 4 + g) * 1024);
                gload16(sl_, u.s.al + (wv * 4 + g) * 1024);
            }
        } else {
#pragma unroll
            for (int g = 0; g < 4; g++) {
                int row = (wv * 4 + g) * 8 + (lane >> 3);
                size_t so = (size_t)(m0 + row) * KTOT + kt * 64 + sl * 8;
                gload16(inH + so, u.s.ah + (wv * 4 + g) * 1024);
                gload16(inL + so, u.s.al + (wv * 4 + g) * 1024);
            }
        }
#pragma unroll
        for (int j2 = 0; j2 < 2; j2++) {
            gload16(wbh + boff[j2] + kt * 64, u.s.bh + (wv * 2 + j2) * 1024);
            gload16(wbl + boff[j2] + kt * 64, u.s.bl + (wv * 2 + j2) * 1024);
        }

        __syncthreads();
#pragma unroll
        for (int hk = 0; hk < 2; hk++) {
            s16x8 ah[4], al[4], bh2[2], bl2[2];
#pragma unroll
            for (int mi = 0; mi < 4; mi++) {
                int row = wm * 64 + mi * 16 + lr;
                int off = row * 128 + (((hk * 4 + lg) ^ (row & 7)) << 4);
                ah[mi] = *(const s16x8*)(u.s.ah + off);
                al[mi] = *(const s16x8*)(u.s.al + off);
            }
#pragma unroll
            for (int ni = 0; ni < 2; ni++) {
                int row = wn * 32 + ni * 16 + lr;
                int off = row * 128 + (((hk * 4 + lg) ^ (row & 7)) << 4);
                bh2[ni] = *(const s16x8*)(u.s.bh + off);
                bl2[ni] = *(const s16x8*)(u.s.bl + off);
            }
#pragma unroll
            for (int mi = 0; mi < 4; mi++)
#pragma unroll
                for (int ni = 0; ni < 2; ni++) {
                    acc[mi][ni] = __builtin_amdgcn_mfma_f32_16x16x32_bf16(
                        ah[mi], bh2[ni], acc[mi][ni], 0, 0, 0);
                    acc[mi][ni] = __builtin_amdgcn_mfma_f32_16x16x32_bf16(
                        al[mi], bh2[ni], acc[mi][ni], 0, 0, 0);
                    acc[mi][ni] = __builtin_amdgcn_mfma_f32_16x16x32_bf16(
                        ah[mi], bl2[ni], acc[mi][ni], 0, 0, 0);
                }
        }
        __syncthreads();
    }

    // ---- epilogue: bias, LDS transpose, fp32 NHWC store, fused BN stats ----
    if (STATS && tid < 128) ((float*)blkstat)[tid] = 0.f;
#pragma unroll
    for (int mi = 0; mi < 4; mi++)
#pragma unroll
        for (int ni = 0; ni < 2; ni++)
#pragma unroll
            for (int r = 0; r < 4; r++)
                u.c[wm * 64 + mi * 16 + lg * 4 + r][wn * 32 + ni * 16 + lr] = acc[mi][ni][r] + bv[ni];
    __syncthreads();

    const int chunk = tid & 7, rbase = tid >> 3;
    float ss[8] = {0,0,0,0,0,0,0,0}, qq[8] = {0,0,0,0,0,0,0,0};
#pragma unroll
    for (int i = 0; i < 4; i++) {
        int row = rbase + i * 32;
        float v[8];
#pragma unroll
        for (int j = 0; j < 8; j++) {
            v[j] = u.c[row][chunk * 8 + j];
            if (STATS) { ss[j] += v[j]; qq[j] += v[j] * v[j]; }
        }
        size_t base = (size_t)(m0 + row) * COUT + n0 + chunk * 8;
        *(float4*)&out[base]     = make_float4(v[0], v[1], v[2], v[3]);
        *(float4*)&out[base + 4] = make_float4(v[4], v[5], v[6], v[7]);
    }
    if (STATS) {
#pragma unroll
        for (int j = 0; j < 8; j++) {
            atomicAdd(&blkstat[chunk * 8 + j][0], ss[j]);
            atomicAdd(&blkstat[chunk * 8 + j][1], qq[j]);
        }
        __syncthreads();
        if (tid < 64) {
            atomicAdd(&gsum[n0 + tid], blkstat[tid][0]);
            atomicAdd(&gsq[n0 + tid],  blkstat[tid][1]);
        }
    }
}

// ================= BN finalize: A=g*rsqrt(var+eps), B=b-mu*A ===============
__global__ void bn_finalize(const float* __restrict__ sum, const float* __restrict__ sq,
                            const float* __restrict__ g, const float* __restrict__ b,
                            float* __restrict__ A, float* __restrict__ Bc,
                            int C, float invN)
{
    int c = threadIdx.x;
    if (c < C) {
        float mu  = sum[c] * invN;
        float var = sq[c] * invN - mu * mu;
        float s   = rsqrtf(var + 1e-5f) * g[c];
        A[c]  = s;
        Bc[c] = b[c] - mu * s;
    }
}

// ==== BN affine + relu + 2x2 maxpool (fp32 NHWC in -> hi/lo bf16 planes) ===
template<int CC, int HH, int WW>
__global__ __launch_bounds__(256)
void bnpool_kernel(const float* __restrict__ in, const float* __restrict__ A,
                   const float* __restrict__ Bc, ushort* __restrict__ outH,
                   ushort* __restrict__ outL)
{
    constexpr int CH = CC / 8, PW = WW / 2, PH = HH / 2;
    int i = blockIdx.x * 256 + threadIdx.x;
    int cc = i & (CH - 1);
    int t2 = i / CH;
    int px = t2 & (PW - 1);
    int t3 = t2 / PW;
    int py = t3 & (PH - 1);
    int b  = t3 / PH;
    const float* p = in + (size_t)((b * HH + 2 * py) * WW + 2 * px) * CC + cc * 8;
    float v00[8], v01[8], v10[8], v11[8];
#pragma unroll
    for (int j = 0; j < 8; j++) {
        v00[j] = p[j];
        v01[j] = p[CC + j];
        v10[j] = p[(size_t)WW * CC + j];
        v11[j] = p[(size_t)WW * CC + CC + j];
    }
    unsigned pwh[4], pwl[4];
#pragma unroll
    for (int jj = 0; jj < 4; jj++) {
        ushort h2[2], l2[2];
#pragma unroll
        for (int k = 0; k < 2; k++) {
            int j = jj * 2 + k;
            int c = cc * 8 + j;
            float Av = A[c], Bv = Bc[c];
            float m = fmaxf(fmaxf(fmaf(v00[j], Av, Bv), fmaf(v01[j], Av, Bv)),
                            fmaxf(fmaf(v10[j], Av, Bv), fmaf(v11[j], Av, Bv)));
            m = fmaxf(m, 0.f);
            h2[k] = f2b(m);
            l2[k] = f2b(m - b2f(h2[k]));
        }
        pwh[jj] = (unsigned)h2[0] | ((unsigned)h2[1] << 16);
        pwl[jj] = (unsigned)l2[0] | ((unsigned)l2[1] << 16);
    }
    *(uint4*)&outH[(size_t)i * 8] = make_uint4(pwh[0], pwh[1], pwh[2], pwh[3]);
    *(uint4*)&outL[(size_t)i * 8] = make_uint4(pwl[0], pwl[1], pwl[2], pwl[3]);
}

// ======== conv1 (1->64, 64x64, fp32): MODE1 stats / MODE2 pool->planes =====
template<int MODE>
__global__ __launch_bounds__(256)
void conv1_kernel(const float* __restrict__ in, const float* __restrict__ wgt,
                  const float* __restrict__ bias, ushort* __restrict__ outH,
                  ushort* __restrict__ outL,
                  float* __restrict__ ssum, float* __restrict__ ssq,
                  const float* __restrict__ bnA, const float* __restrict__ bnB)
{
    __shared__ float slab[34][34];
    __shared__ float redbuf[4 * 8 * 2];
    const int tid = threadIdx.x;
    const int bg = blockIdx.x >> 2, tile = blockIdx.x & 3;
    const int ty = (tile >> 1) * 32, tx = (tile & 1) * 32;
    const int cout0 = blockIdx.y * 8;
    const int qy = tid >> 4, qx = tid & 15;
    const int oy = ty + 2 * qy, ox = tx + 2 * qx;

    for (int idx = tid; idx < 34 * 34; idx += 256) {
        int sy = idx / 34, sx = idx - sy * 34;
        int gy = ty + sy - 1, gx = tx + sx - 1;
        float v = 0.f;
        if (gy >= 0 && gy < 64 && gx >= 0 && gx < 64)
            v = in[((size_t)bg * 64 + gy) * 64 + gx];
        (&slab[0][0])[idx] = v;
    }
    __syncthreads();
    float v[4][4];
#pragma unroll
    for (int r = 0; r < 4; r++) {
        float2 a = *(const float2*)&slab[2 * qy + r][2 * qx];
        float2 b = *(const float2*)&slab[2 * qy + r][2 * qx + 2];
        v[r][0] = a.x; v[r][1] = a.y; v[r][2] = b.x; v[r][3] = b.y;
    }
    float acc[4][8];
#pragma unroll
    for (int oc = 0; oc < 8; oc++) {
        const float* w9 = wgt + (size_t)(cout0 + oc) * 9;
        float w0 = w9[0], w1 = w9[1], w2 = w9[2], w3 = w9[3], w4 = w9[4],
              w5 = w9[5], w6 = w9[6], w7 = w9[7], w8 = w9[8];
        float bs = bias[cout0 + oc];
#pragma unroll
        for (int dy = 0; dy < 2; dy++)
#pragma unroll
            for (int dx = 0; dx < 2; dx++) {
                float s = bs;
                s = fmaf(w0, v[dy][dx], s);
                s = fmaf(w1, v[dy][dx + 1], s);
                s = fmaf(w2, v[dy][dx + 2], s);
                s = fmaf(w3, v[dy + 1][dx], s);
                s = fmaf(w4, v[dy + 1][dx + 1], s);
                s = fmaf(w5, v[dy + 1][dx + 2], s);
                s = fmaf(w6, v[dy + 2][dx], s);
                s = fmaf(w7, v[dy + 2][dx + 1], s);
                s = fmaf(w8, v[dy + 2][dx + 2], s);
                acc[dy * 2 + dx][oc] = s;
            }
    }
    if constexpr (MODE == 1) {
        int wave = tid >> 6, lanei = tid & 63;
#pragma unroll
        for (int oc = 0; oc < 8; oc++) {
            float s  = acc[0][oc] + acc[1][oc] + acc[2][oc] + acc[3][oc];
            float q2 = acc[0][oc] * acc[0][oc] + acc[1][oc] * acc[1][oc] +
                       acc[2][oc] * acc[2][oc] + acc[3][oc] * acc[3][oc];
#pragma unroll
            for (int off = 32; off > 0; off >>= 1) {
                s  += __shfl_down(s, off);
                q2 += __shfl_down(q2, off);
            }
            if (lanei == 0) {
                redbuf[(wave * 8 + oc) * 2 + 0] = s;
                redbuf[(wave * 8 + oc) * 2 + 1] = q2;
            }
        }
        __syncthreads();
        if (tid < 8) {
            float s = 0.f, q2 = 0.f;
#pragma unroll
            for (int w = 0; w < 4; w++) {
                s  += redbuf[(w * 8 + tid) * 2 + 0];
                q2 += redbuf[(w * 8 + tid) * 2 + 1];
            }
            atomicAdd(&ssum[cout0 + tid], s);
            atomicAdd(&ssq[cout0 + tid], q2);
        }
    }
    if constexpr (MODE == 2) {
        unsigned pwh[4], pwl[4];
#pragma unroll
        for (int jj = 0; jj < 4; jj++) {
            ushort h2[2], l2[2];
#pragma unroll
            for (int k = 0; k < 2; k++) {
                int oc = jj * 2 + k;
                float Av = bnA[cout0 + oc], Bv = bnB[cout0 + oc];
                float m0_ = fmaxf(fmaf(acc[0][oc], Av, Bv), fmaf(acc[1][oc], Av, Bv));
                float m1_ = fmaxf(fmaf(acc[2][oc], Av, Bv), fmaf(acc[3][oc], Av, Bv));
                float m = fmaxf(fmaxf(m0_, m1_), 0.f);
                h2[k] = f2b(m);
                l2[k] = f2b(m - b2f(h2[k]));
            }
            pwh[jj] = (unsigned)h2[0] | ((unsigned)h2[1] << 16);
            pwl[jj] = (unsigned)l2[0] | ((unsigned)l2[1] << 16);
        }
        size_t base = (size_t)((bg * 32 + (oy >> 1)) * 32 + (ox >> 1)) * 64 + cout0;
        *(uint4*)&outH[base] = make_uint4(pwh[0], pwh[1], pwh[2], pwh[3]);
        *(uint4*)&outL[base] = make_uint4(pwl[0], pwl[1], pwl[2], pwl[3]);
    }
}

// =============== offset conv: 256 -> 18 channels at 4x4 (fp32) =============
__global__ __launch_bounds__(256)
void offconv_kernel(const ushort* __restrict__ hH, const ushort* __restrict__ hL,
                    const float* __restrict__ ow, const float* __restrict__ ob,
                    float* __restrict__ off)
{
    __shared__ float plane[256][36];
    int b = blockIdx.x, tid = threadIdx.x;
    for (int i = tid; i < 256 * 36; i += 256) (&plane[0][0])[i] = 0.f;
    __syncthreads();
    for (int i = tid; i < 4096; i += 256) {
        int px = i >> 8, c = i & 255;
        size_t idx = ((size_t)b * 16 + px) * 256 + c;
        plane[c][((px >> 2) + 1) * 6 + (px & 3) + 1] = b2f(hH[idx]) + b2f(hL[idx]);
    }
    __syncthreads();
    for (int o = tid; o < 288; o += 256) {
        int co = o >> 4, px = o & 15, y = px >> 2, x = px & 3;
        float s = ob[co];
        const float* wb = ow + (size_t)co * 256 * 9;
        for (int c = 0; c < 256; c++) {
            const float* wc = wb + c * 9;
            const float* pl = &plane[c][y * 6 + x];
#pragma unroll
            for (int r = 0; r < 3; r++)
#pragma unroll
                for (int k = 0; k < 3; k++)
                    s = fmaf(wc[r * 3 + k], pl[r * 6 + k], s);
        }
        off[((size_t)b * 18 + co) * 16 + px] = s;
    }
}

// ====== deformable sampling -> xo hi/lo bf16 planes [2048][2304] ===========
__global__ __launch_bounds__(256)
void sample_kernel(const ushort* __restrict__ hH, const ushort* __restrict__ hL,
                   const float* __restrict__ off, ushort* __restrict__ xoH,
                   ushort* __restrict__ xoL)
{
    __shared__ float plane[256][36];
    __shared__ int   tidx[144][4];
    __shared__ float twt[144][4];
    int b = blockIdx.x, tid = threadIdx.x;
    for (int i = tid; i < 256 * 36; i += 256) (&plane[0][0])[i] = 0.f;
    __syncthreads();
    for (int i = tid; i < 4096; i += 256) {
        int px = i >> 8, c = i & 255;
        size_t idx = ((size_t)b * 16 + px) * 256 + c;
        plane[c][((px >> 2) + 1) * 6 + (px & 3) + 1] = b2f(hH[idx]) + b2f(hL[idx]);
    }
    if (tid < 144) {
        int px = tid / 9, n = tid % 9;
        int y = px >> 2, x = px & 3;
        float ox_ = off[((size_t)b * 18 + 2 * n) * 16 + px];
        float oy_ = off[((size_t)b * 18 + 2 * n + 1) * 16 + px];
        float pxc = (float)(y + 1) + (float)(n / 3 - 1) + ox_;
        float pyc = (float)(x + 1) + (float)(n % 3 - 1) + oy_;
        if (pxc < 1.f || pxc > 4.f) pxc = floorf(pxc);
        if (pyc < 1.f || pyc > 4.f) pyc = floorf(pyc);
        pxc = fminf(fmaxf(pxc, 0.f), 5.f);
        pyc = fminf(fmaxf(pyc, 0.f), 5.f);
        float fx = floorf(pxc), fy = floorf(pyc);
        float qrbx = fminf(fx + 1.f, 5.f), qrby = fminf(fy + 1.f, 5.f);
        float wx_lt = 1.f + (fx - pxc), wx_rb = 1.f - (qrbx - pxc);
        float wy_lt = 1.f + (fy - pyc), wy_rb = 1.f - (qrby - pyc);
        tidx[tid][0] = (int)(fx * 6.f + fy);     twt[tid][0] = wx_lt * wy_lt;
        tidx[tid][1] = (int)(qrbx * 6.f + qrby); twt[tid][1] = wx_rb * wy_rb;
        tidx[tid][2] = (int)(fx * 6.f + qrby);   twt[tid][2] = wx_lt * wy_rb;
        tidx[tid][3] = (int)(qrbx * 6.f + fy);   twt[tid][3] = wx_rb * wy_lt;
    }
    __syncthreads();
    for (int s = tid; s < 36864; s += 256) {
        int px = s / 2304, k = s - px * 2304;
        int c = k / 9, n = k - c * 9;
        int t = px * 9 + n;
        const float* pc = plane[c];
        float v = twt[t][0] * pc[tidx[t][0]] + twt[t][1] * pc[tidx[t][1]] +
                  twt[t][2] * pc[tidx[t][2]] + twt[t][3] * pc[tidx[t][3]];
        ushort h = f2b(v);
        size_t o = ((size_t)b * 16 + px) * 2304 + k;
        xoH[o] = h;
        xoL[o] = f2b(v - b2f(h));
    }
}

// ============== bn5 stats over relu(dout fp32) =============================
__global__ __launch_bounds__(256)
void stats5_kernel(const float* __restrict__ dout, float* __restrict__ sum5,
                   float* __restrict__ sq5)
{
    __shared__ float rs[256], rq[256];
    int c = blockIdx.x, tid = threadIdx.x;
    float s = 0.f, q = 0.f;
    for (int i = tid; i < 2048; i += 256) {
        float v = fmaxf(dout[(size_t)i * 256 + c], 0.f);
        s += v; q += v * v;
    }
    rs[tid] = s; rq[tid] = q; __syncthreads();
    for (int st = 128; st > 0; st >>= 1) {
        if (tid < st) { rs[tid] += rs[tid + st]; rq[tid] += rq[tid + st]; }
        __syncthreads();
    }
    if (tid == 0) { sum5[c] = rs[0]; sq5[c] = rq[0]; }
}

// ====== head: relu -> bn5 folded into mean -> fc -> log_softmax ============
__global__ __launch_bounds__(256)
void final_kernel(const float* __restrict__ dout, const float* __restrict__ A5,
                  const float* __restrict__ B5, const float* __restrict__ fcw,
                  const float* __restrict__ fcb, float* __restrict__ out)
{
    __shared__ float hbar[256];
    __shared__ float red[256];
    int b = blockIdx.x, tid = threadIdx.x;
    float s = 0.f;
#pragma unroll 4
    for (int px = 0; px < 16; px++)
        s += fmaxf(dout[((size_t)b * 16 + px) * 256 + tid], 0.f);
    hbar[tid] = fmaf(A5[tid], s * (1.f / 16.f), B5[tid]);
    __syncthreads();
    float logit = -1e30f;
    if (tid < 250) {
        float acc = fcb[tid];
        const float4* wr = (const float4*)(fcw + (size_t)tid * 256);
        const float4* hv = (const float4*)hbar;
#pragma unroll 4
        for (int i = 0; i < 64; i++) {
            float4 w4 = wr[i], h4 = hv[i];
            acc = fmaf(w4.x, h4.x, acc); acc = fmaf(w4.y, h4.y, acc);
            acc = fmaf(w4.z, h4.z, acc); acc = fmaf(w4.w, h4.w, acc);
        }
        logit = acc;
    }
    red[tid] = logit; __syncthreads();
    for (int st = 128; st > 0; st >>= 1) {
        if (tid < st) red[tid] = fmaxf(red[tid], red[tid + st]);
        __syncthreads();
    }
    float mx = red[0]; __syncthreads();
    float e = (tid < 250) ? expf(logit - mx) : 0.f;
    red[tid] = e; __syncthreads();
    for (int st = 128; st > 0; st >>= 1) {
        if (tid < st) red[tid] += red[tid + st];
        __syncthreads();
    }
    float lse = logf(red[0]) + mx;
    if (tid < 250) out[(size_t)b * 250 + tid] = logit - lse;
}

// ===========================================================================
extern "C" void kernel_launch(void* const* d_in, const int* in_sizes, int n_in,
                              void* d_out, int out_size, void* d_ws, size_t ws_size,
                              hipStream_t stream)
{
    const float* s_in = (const float*)d_in[0];
    const float* c1w = (const float*)d_in[1];  const float* c1b = (const float*)d_in[2];
    const float* g1  = (const float*)d_in[3];  const float* b1  = (const float*)d_in[4];
    const float* c2w = (const float*)d_in[5];  const float* c2b = (const float*)d_in[6];
    const float* g2  = (const float*)d_in[7];  const float* b2  = (const float*)d_in[8];
    const float* c3w = (const float*)d_in[9];  const float* c3b = (const float*)d_in[10];
    const float* g3  = (const float*)d_in[11]; const float* b3  = (const float*)d_in[12];
    const float* c4w = (const float*)d_in[13]; const float* c4b = (const float*)d_in[14];
    const float* g4  = (const float*)d_in[15]; const float* b4  = (const float*)d_in[16];
    const float* ofw = (const float*)d_in[17]; const float* ofb = (const float*)d_in[18];
    const float* dcw = (const float*)d_in[19];
    const float* g5  = (const float*)d_in[20]; const float* b5  = (const float*)d_in[21];
    const float* fcw = (const float*)d_in[22]; const float* fcb = (const float*)d_in[23];

    float* ws   = (float*)d_ws;
    float* stat = ws;                       // 2560
    float* ab   = ws + 2560;                // 2560
    float* zpad = ws + 5120;                // 64
    // bf16 hi/lo weight planes (float offsets; sizes in ushorts = 2x floats)
    ushort* w2h = (ushort*)(ws + 5184);     // 73728 u
    ushort* w2l = (ushort*)(ws + 42048);
    ushort* w3h = (ushort*)(ws + 78912);    // 294912 u
    ushort* w3l = (ushort*)(ws + 226368);
    ushort* w4h = (ushort*)(ws + 373824);   // 589824 u
    ushort* w4l = (ushort*)(ws + 668736);
    ushort* wdh = (ushort*)(ws + 963648);   // 589824 u
    ushort* wdl = (ushort*)(ws + 1258560);
    ushort* poolH = (ushort*)(ws + 1553472);  // 8,388,608 u max
    ushort* poolL = (ushort*)(ws + 5747776);
    float*  conv32 = ws + 9942080;            // 16,777,216 f max (reused below)
    ushort* xoH  = (ushort*)(ws + 9942080);   // 4,718,592 u
    ushort* xoL  = (ushort*)(ws + 12301376);
    float*  dout = ws + 14660672;             // 524,288 f
    float*  offb = ws + 15184960;             // 36,864 f

    hipMemsetAsync(stat, 0, 2048 * sizeof(float), stream);
    hipMemsetAsync(zpad, 0, 256, stream);

    // weight split-conversions
    wcvt_kernel<<<(128 * 64 * 9 + 255) / 256, 256, 0, stream>>>(c2w, w2h, w2l, 64, 1, 128 * 64 * 9);
    wcvt_kernel<<<(256 * 128 * 9 + 255) / 256, 256, 0, stream>>>(c3w, w3h, w3l, 128, 1, 256 * 128 * 9);
    wcvt_kernel<<<(256 * 256 * 9 + 255) / 256, 256, 0, stream>>>(c4w, w4h, w4l, 256, 1, 256 * 256 * 9);
    wcvt_kernel<<<(256 * 2304 + 255) / 256, 256, 0, stream>>>(dcw, wdh, wdl, 256, 0, 256 * 2304);

    // ---- stage 1: conv1 (recompute trick) -> hi/lo NHWC [B,32,32,64] ----
    conv1_kernel<1><<<dim3(512, 8), 256, 0, stream>>>(s_in, c1w, c1b, nullptr, nullptr,
                                                      stat, stat + 256, nullptr, nullptr);
    bn_finalize<<<1, 256, 0, stream>>>(stat, stat + 256, g1, b1, ab, ab + 256, 64,
                                       1.0f / (128.f * 64.f * 64.f));
    conv1_kernel<2><<<dim3(512, 8), 256, 0, stream>>>(s_in, c1w, c1b, poolH, poolL,
                                                      nullptr, nullptr, ab, ab + 256);

    // ---- stage 2: conv2 GEMM (M=131072, N=128, K=576) ----
    gemm_kernel<576, 64, 32, 32, 128, true, true, true><<<dim3(1024, 2), 256, 0, stream>>>(
        poolH, poolL, w2h, w2l, c2b, conv32, (const ushort*)zpad, stat + 512, stat + 768);
    bn_finalize<<<1, 256, 0, stream>>>(stat + 512, stat + 768, g2, b2, ab + 512, ab + 768,
                                       128, 1.0f / (128.f * 32.f * 32.f));
    bnpool_kernel<128, 32, 32><<<2048, 256, 0, stream>>>(conv32, ab + 512, ab + 768, poolH, poolL);

    // ---- stage 3: conv3 GEMM (M=32768, N=256, K=1152) ----
    gemm_kernel<1152, 128, 16, 16, 256, true, true, true><<<dim3(256, 4), 256, 0, stream>>>(
        poolH, poolL, w3h, w3l, c3b, conv32, (const ushort*)zpad, stat + 1024, stat + 1280);
    bn_finalize<<<1, 256, 0, stream>>>(stat + 1024, stat + 1280, g3, b3, ab + 1024, ab + 1280,
                                       256, 1.0f / (128.f * 16.f * 16.f));
    bnpool_kernel<256, 16, 16><<<1024, 256, 0, stream>>>(conv32, ab + 1024, ab + 1280, poolH, poolL);

    // ---- stage 4: conv4 GEMM (M=8192, N=256, K=2304) ----
    gemm_kernel<2304, 256, 8, 8, 256, true, true, true><<<dim3(64, 4), 256, 0, stream>>>(
        poolH, poolL, w4h, w4l, c4b, conv32, (const ushort*)zpad, stat + 1536, stat + 1792);
    bn_finalize<<<1, 256, 0, stream>>>(stat + 1536, stat + 1792, g4, b4, ab + 1536, ab + 1792,
                                       256, 1.0f / (128.f * 8.f * 8.f));
    bnpool_kernel<256, 8, 8><<<256, 256, 0, stream>>>(conv32, ab + 1536, ab + 1792, poolH, poolL);

    // ---- deformable conv ----
    offconv_kernel<<<128, 256, 0, stream>>>(poolH, poolL, ofw, ofb, offb);
    sample_kernel<<<128, 256, 0, stream>>>(poolH, poolL, offb, xoH, xoL);
    gemm_kernel<2304, 2304, 1, 1, 256, false, false, false><<<dim3(16, 4), 256, 0, stream>>>(
        xoH, xoL, wdh, wdl, nullptr, dout, (const ushort*)zpad, nullptr, nullptr);

    // ---- bn5 + head ----
    stats5_kernel<<<256, 256, 0, stream>>>(dout, stat + 2048, stat + 2304);
    bn_finalize<<<1, 256, 0, stream>>>(stat + 2048, stat + 2304, g5, b5, ab + 2048, ab + 2304,
                                       256, 1.0f / 2048.f);
    final_kernel<<<128, 256, 0, stream>>>(dout, ab + 2048, ab + 2304, fcw, fcb, (float*)d_out);
}

// Round 4
// 548.189 us; speedup vs baseline: 3.3995x; 1.2636x over previous
//
#include <hip/hip_runtime.h>
#include <math.h>

typedef float  f32x4 __attribute__((ext_vector_type(4)));
typedef short  s16x8 __attribute__((ext_vector_type(8)));

__device__ __forceinline__ float b2f(ushort u) { return __uint_as_float(((unsigned)u) << 16); }
__device__ __forceinline__ ushort f2b(float f) {
    unsigned u = __float_as_uint(f);
    return (ushort)((u + 0x7FFFu + ((u >> 16) & 1u)) >> 16);
}
__device__ __forceinline__ void gload16(const void* g, void* l) {
    __builtin_amdgcn_global_load_lds((const __attribute__((address_space(1))) void*)g,
                                     (__attribute__((address_space(3))) void*)l, 16, 0, 0);
}

// ====== weight convert: fp32 OIHW -> bf16 hi/lo planes [CO][ksp*CI+ci] =====
__global__ __launch_bounds__(256)
void wcvt_kernel(const float* __restrict__ src, ushort* __restrict__ dsth,
                 ushort* __restrict__ dstl, int CI, int reorder, int total)
{
    int i = blockIdx.x * 256 + threadIdx.x;
    if (i >= total) return;
    float v;
    if (reorder) {
        int k9 = CI * 9;
        int co = i / k9; int rem = i - co * k9;
        int ksp = rem / CI; int ci = rem - ksp * CI;
        v = src[(size_t)(co * CI + ci) * 9 + ksp];
    } else {
        v = src[i];
    }
    ushort h = f2b(v);
    dsth[i] = h;
    dstl[i] = f2b(v - b2f(h));
}

// ================= split-bf16 MFMA implicit-GEMM (2-phase dbuf) ============
// out[M][COUT] (fp32) = A[M][K] * W[COUT][K]^T (+bias); A,W hi/lo bf16 planes;
// acc += ah*wh + al*wh + ah*wl. BM=128, BN=64, BK=32; 4 waves (2x2).
// Double-buffered LDS, stage-ahead, one barrier per K-step (T3 minimum).
template<int KTOT, int CIN, int HH, int WW, int COUT, bool IM2COL, bool BIAS, bool STATS>
__global__ __launch_bounds__(256)
void gemm_kernel(const ushort* __restrict__ inH, const ushort* __restrict__ inL,
                 const ushort* __restrict__ wbh, const ushort* __restrict__ wbl,
                 const float* __restrict__ bias, float* __restrict__ out,
                 const ushort* __restrict__ zsrc0,
                 float* __restrict__ gsum, float* __restrict__ gsq)
{
    constexpr int BUF = 24576;   // ah 8K | al 8K | bh 4K | bl 4K
    __shared__ union {
        char s[2 * BUF];
        float c[128][66];
    } u;
    __shared__ float blkstat[64][2];

    const int tid  = threadIdx.x;
    const int lane = tid & 63, wv = tid >> 6;
    const int lr = lane & 15, lg = lane >> 4;
    const int wm = wv >> 1,  wn = wv & 1;
    int gx = blockIdx.x;
    gx = (gx & 7) * (gridDim.x >> 3) + (gx >> 3);   // bijective XCD swizzle (grid.x % 8 == 0)
    const int m0 = gx * 128;
    const int n0 = blockIdx.y * 64;

    // ---- staging precompute (thread stages phys chunk sch of rows arow[q]) ----
    const int sch = tid & 3;
    int aco[2], apix[2], ay[2] = {0,0}, ax[2] = {0,0};
#pragma unroll
    for (int q = 0; q < 2; q++) {
        int row = (tid >> 2) + q * 64;
        aco[q] = ((sch ^ ((row >> 1) & 3)) << 3);     // swizzled source elem offset
        int m = m0 + row;
        apix[q] = m;
        if constexpr (IM2COL) {
            int rem = m & (HH * WW - 1);
            ay[q] = rem / WW;
            ax[q] = rem & (WW - 1);
        }
    }
    const int brow = tid >> 2;
    const size_t bbase = (size_t)(n0 + brow) * KTOT + ((sch ^ ((brow >> 1) & 3)) << 3);

    // ---- fragment read offsets (chunk_p per-lane constant, conflict-free) ----
    const int chunk_p = (lg ^ ((lr >> 1) & 3)) << 4;
    int afoff[4], bfoff[2];
#pragma unroll
    for (int mi = 0; mi < 4; mi++) afoff[mi] = (wm * 64 + mi * 16 + lr) * 64 + chunk_p;
#pragma unroll
    for (int ni = 0; ni < 2; ni++) bfoff[ni] = 16384 + (wn * 32 + ni * 16 + lr) * 64 + chunk_p;

    float bv[2] = {0.f, 0.f};
    if (BIAS) { bv[0] = bias[n0 + wn * 32 + lr]; bv[1] = bias[n0 + wn * 32 + 16 + lr]; }

    f32x4 acc[4][2] = {};
    constexpr int NK = KTOT / 32;

    auto stage = [&](int kt, int buf) {
        char* dst = u.s + buf * BUF;
        char* dA = dst + wv * 1024;            // + q*4096; lane*16 added by HW
        char* dB = dst + 16384 + wv * 1024;
        if constexpr (IM2COL) {
            int ksp = (kt * 32) / CIN;
            int c0  = (kt * 32) & (CIN - 1);
            int d3  = ksp / 3;
            int dy = d3 - 1, dx = ksp - d3 * 3 - 1;
            int dpix = dy * WW + dx;
#pragma unroll
            for (int q = 0; q < 2; q++) {
                int iy = ay[q] + dy, ix = ax[q] + dx;
                bool ok = ((unsigned)iy < (unsigned)HH) && ((unsigned)ix < (unsigned)WW);
                size_t so = (size_t)(apix[q] + dpix) * CIN + c0 + aco[q];
                gload16(ok ? (const void*)(inH + so) : (const void*)(zsrc0 + aco[q]),
                        dA + q * 4096);
                gload16(ok ? (const void*)(inL + so) : (const void*)(zsrc0 + aco[q]),
                        dA + 8192 + q * 4096);
            }
        } else {
#pragma unroll
            for (int q = 0; q < 2; q++) {
                size_t so = (size_t)apix[q] * KTOT + kt * 32 + aco[q];
                gload16(inH + so, dA + q * 4096);
                gload16(inL + so, dA + 8192 + q * 4096);
            }
        }
        gload16(wbh + bbase + kt * 32, dB);
        gload16(wbl + bbase + kt * 32, dB + 4096);
    };

    stage(0, 0);
    __syncthreads();
    int cur = 0;
#pragma unroll 1
    for (int kt = 0; kt < NK; kt++) {
        if (kt + 1 < NK) stage(kt + 1, cur ^ 1);
        const char* base = u.s + cur * BUF;
        s16x8 ah4[4], al4[4], bh2[2], bl2[2];
#pragma unroll
        for (int mi = 0; mi < 4; mi++) {
            ah4[mi] = *(const s16x8*)(base + afoff[mi]);
            al4[mi] = *(const s16x8*)(base + afoff[mi] + 8192);
        }
#pragma unroll
        for (int ni = 0; ni < 2; ni++) {
            bh2[ni] = *(const s16x8*)(base + bfoff[ni]);
            bl2[ni] = *(const s16x8*)(base + bfoff[ni] + 4096);
        }
#pragma unroll
        for (int mi = 0; mi < 4; mi++)
#pragma unroll
            for (int ni = 0; ni < 2; ni++) {
                acc[mi][ni] = __builtin_amdgcn_mfma_f32_16x16x32_bf16(
                    ah4[mi], bh2[ni], acc[mi][ni], 0, 0, 0);
                acc[mi][ni] = __builtin_amdgcn_mfma_f32_16x16x32_bf16(
                    al4[mi], bh2[ni], acc[mi][ni], 0, 0, 0);
                acc[mi][ni] = __builtin_amdgcn_mfma_f32_16x16x32_bf16(
                    ah4[mi], bl2[ni], acc[mi][ni], 0, 0, 0);
            }
        __syncthreads();   // emits vmcnt(0) lgkmcnt(0): drains NEXT-tile loads issued pre-compute
        cur ^= 1;
    }

    // ---- epilogue: bias, LDS transpose, fp32 NHWC store, fused BN stats ----
    if (STATS && tid < 128) ((float*)blkstat)[tid] = 0.f;
#pragma unroll
    for (int mi = 0; mi < 4; mi++)
#pragma unroll
        for (int ni = 0; ni < 2; ni++)
#pragma unroll
            for (int r = 0; r < 4; r++)
                u.c[wm * 64 + mi * 16 + lg * 4 + r][wn * 32 + ni * 16 + lr] = acc[mi][ni][r] + bv[ni];
    __syncthreads();

    const int chunk = tid & 7, rbase = tid >> 3;
    float ss[8] = {0,0,0,0,0,0,0,0}, qq[8] = {0,0,0,0,0,0,0,0};
#pragma unroll
    for (int i = 0; i < 4; i++) {
        int row = rbase + i * 32;
        float v[8];
#pragma unroll
        for (int j = 0; j < 8; j++) {
            v[j] = u.c[row][chunk * 8 + j];
            if (STATS) { ss[j] += v[j]; qq[j] += v[j] * v[j]; }
        }
        size_t base = (size_t)(m0 + row) * COUT + n0 + chunk * 8;
        *(float4*)&out[base]     = make_float4(v[0], v[1], v[2], v[3]);
        *(float4*)&out[base + 4] = make_float4(v[4], v[5], v[6], v[7]);
    }
    if (STATS) {
#pragma unroll
        for (int j = 0; j < 8; j++) {
            atomicAdd(&blkstat[chunk * 8 + j][0], ss[j]);
            atomicAdd(&blkstat[chunk * 8 + j][1], qq[j]);
        }
        __syncthreads();
        if (tid < 64) {
            atomicAdd(&gsum[n0 + tid], blkstat[tid][0]);
            atomicAdd(&gsq[n0 + tid],  blkstat[tid][1]);
        }
    }
}

// ================= BN finalize: A=g*rsqrt(var+eps), B=b-mu*A ===============
__global__ void bn_finalize(const float* __restrict__ sum, const float* __restrict__ sq,
                            const float* __restrict__ g, const float* __restrict__ b,
                            float* __restrict__ A, float* __restrict__ Bc,
                            int C, float invN)
{
    int c = threadIdx.x;
    if (c < C) {
        float mu  = sum[c] * invN;
        float var = sq[c] * invN - mu * mu;
        float s   = rsqrtf(var + 1e-5f) * g[c];
        A[c]  = s;
        Bc[c] = b[c] - mu * s;
    }
}

// ==== BN affine + relu + 2x2 maxpool (fp32 NHWC in -> hi/lo bf16 planes) ===
template<int CC, int HH, int WW>
__global__ __launch_bounds__(256)
void bnpool_kernel(const float* __restrict__ in, const float* __restrict__ A,
                   const float* __restrict__ Bc, ushort* __restrict__ outH,
                   ushort* __restrict__ outL)
{
    constexpr int CH = CC / 8, PW = WW / 2, PH = HH / 2;
    int i = blockIdx.x * 256 + threadIdx.x;
    int cc = i & (CH - 1);
    int t2 = i / CH;
    int px = t2 & (PW - 1);
    int t3 = t2 / PW;
    int py = t3 & (PH - 1);
    int b  = t3 / PH;
    const float* p = in + (size_t)((b * HH + 2 * py) * WW + 2 * px) * CC + cc * 8;
    float v00[8], v01[8], v10[8], v11[8];
#pragma unroll
    for (int j = 0; j < 8; j++) {
        v00[j] = p[j];
        v01[j] = p[CC + j];
        v10[j] = p[(size_t)WW * CC + j];
        v11[j] = p[(size_t)WW * CC + CC + j];
    }
    unsigned pwh[4], pwl[4];
#pragma unroll
    for (int jj = 0; jj < 4; jj++) {
        ushort h2[2], l2[2];
#pragma unroll
        for (int k = 0; k < 2; k++) {
            int j = jj * 2 + k;
            int c = cc * 8 + j;
            float Av = A[c], Bv = Bc[c];
            float m = fmaxf(fmaxf(fmaf(v00[j], Av, Bv), fmaf(v01[j], Av, Bv)),
                            fmaxf(fmaf(v10[j], Av, Bv), fmaf(v11[j], Av, Bv)));
            m = fmaxf(m, 0.f);
            h2[k] = f2b(m);
            l2[k] = f2b(m - b2f(h2[k]));
        }
        pwh[jj] = (unsigned)h2[0] | ((unsigned)h2[1] << 16);
        pwl[jj] = (unsigned)l2[0] | ((unsigned)l2[1] << 16);
    }
    *(uint4*)&outH[(size_t)i * 8] = make_uint4(pwh[0], pwh[1], pwh[2], pwh[3]);
    *(uint4*)&outL[(size_t)i * 8] = make_uint4(pwl[0], pwl[1], pwl[2], pwl[3]);
}

// ======== conv1 (1->64, 64x64, fp32): MODE1 stats / MODE2 pool->planes =====
template<int MODE>
__global__ __launch_bounds__(256)
void conv1_kernel(const float* __restrict__ in, const float* __restrict__ wgt,
                  const float* __restrict__ bias, ushort* __restrict__ outH,
                  ushort* __restrict__ outL,
                  float* __restrict__ ssum, float* __restrict__ ssq,
                  const float* __restrict__ bnA, const float* __restrict__ bnB)
{
    __shared__ float slab[34][34];
    __shared__ float redbuf[4 * 8 * 2];
    const int tid = threadIdx.x;
    const int bg = blockIdx.x >> 2, tile = blockIdx.x & 3;
    const int ty = (tile >> 1) * 32, tx = (tile & 1) * 32;
    const int cout0 = blockIdx.y * 8;
    const int qy = tid >> 4, qx = tid & 15;
    const int oy = ty + 2 * qy, ox = tx + 2 * qx;

    for (int idx = tid; idx < 34 * 34; idx += 256) {
        int sy = idx / 34, sx = idx - sy * 34;
        int gy = ty + sy - 1, gx = tx + sx - 1;
        float v = 0.f;
        if (gy >= 0 && gy < 64 && gx >= 0 && gx < 64)
            v = in[((size_t)bg * 64 + gy) * 64 + gx];
        (&slab[0][0])[idx] = v;
    }
    __syncthreads();
    float v[4][4];
#pragma unroll
    for (int r = 0; r < 4; r++) {
        float2 a = *(const float2*)&slab[2 * qy + r][2 * qx];
        float2 b = *(const float2*)&slab[2 * qy + r][2 * qx + 2];
        v[r][0] = a.x; v[r][1] = a.y; v[r][2] = b.x; v[r][3] = b.y;
    }
    float acc[4][8];
#pragma unroll
    for (int oc = 0; oc < 8; oc++) {
        const float* w9 = wgt + (size_t)(cout0 + oc) * 9;
        float w0 = w9[0], w1 = w9[1], w2 = w9[2], w3 = w9[3], w4 = w9[4],
              w5 = w9[5], w6 = w9[6], w7 = w9[7], w8 = w9[8];
        float bs = bias[cout0 + oc];
#pragma unroll
        for (int dy = 0; dy < 2; dy++)
#pragma unroll
            for (int dx = 0; dx < 2; dx++) {
                float s = bs;
                s = fmaf(w0, v[dy][dx], s);
                s = fmaf(w1, v[dy][dx + 1], s);
                s = fmaf(w2, v[dy][dx + 2], s);
                s = fmaf(w3, v[dy + 1][dx], s);
                s = fmaf(w4, v[dy + 1][dx + 1], s);
                s = fmaf(w5, v[dy + 1][dx + 2], s);
                s = fmaf(w6, v[dy + 2][dx], s);
                s = fmaf(w7, v[dy + 2][dx + 1], s);
                s = fmaf(w8, v[dy + 2][dx + 2], s);
                acc[dy * 2 + dx][oc] = s;
            }
    }
    if constexpr (MODE == 1) {
        int wave = tid >> 6, lanei = tid & 63;
#pragma unroll
        for (int oc = 0; oc < 8; oc++) {
            float s  = acc[0][oc] + acc[1][oc] + acc[2][oc] + acc[3][oc];
            float q2 = acc[0][oc] * acc[0][oc] + acc[1][oc] * acc[1][oc] +
                       acc[2][oc] * acc[2][oc] + acc[3][oc] * acc[3][oc];
#pragma unroll
            for (int off = 32; off > 0; off >>= 1) {
                s  += __shfl_down(s, off);
                q2 += __shfl_down(q2, off);
            }
            if (lanei == 0) {
                redbuf[(wave * 8 + oc) * 2 + 0] = s;
                redbuf[(wave * 8 + oc) * 2 + 1] = q2;
            }
        }
        __syncthreads();
        if (tid < 8) {
            float s = 0.f, q2 = 0.f;
#pragma unroll
            for (int w = 0; w < 4; w++) {
                s  += redbuf[(w * 8 + tid) * 2 + 0];
                q2 += redbuf[(w * 8 + tid) * 2 + 1];
            }
            atomicAdd(&ssum[cout0 + tid], s);
            atomicAdd(&ssq[cout0 + tid], q2);
        }
    }
    if constexpr (MODE == 2) {
        unsigned pwh[4], pwl[4];
#pragma unroll
        for (int jj = 0; jj < 4; jj++) {
            ushort h2[2], l2[2];
#pragma unroll
            for (int k = 0; k < 2; k++) {
                int oc = jj * 2 + k;
                float Av = bnA[cout0 + oc], Bv = bnB[cout0 + oc];
                float m0_ = fmaxf(fmaf(acc[0][oc], Av, Bv), fmaf(acc[1][oc], Av, Bv));
                float m1_ = fmaxf(fmaf(acc[2][oc], Av, Bv), fmaf(acc[3][oc], Av, Bv));
                float m = fmaxf(fmaxf(m0_, m1_), 0.f);
                h2[k] = f2b(m);
                l2[k] = f2b(m - b2f(h2[k]));
            }
            pwh[jj] = (unsigned)h2[0] | ((unsigned)h2[1] << 16);
            pwl[jj] = (unsigned)l2[0] | ((unsigned)l2[1] << 16);
        }
        size_t base = (size_t)((bg * 32 + (oy >> 1)) * 32 + (ox >> 1)) * 64 + cout0;
        *(uint4*)&outH[base] = make_uint4(pwh[0], pwh[1], pwh[2], pwh[3]);
        *(uint4*)&outL[base] = make_uint4(pwl[0], pwl[1], pwl[2], pwl[3]);
    }
}

// =============== offset conv: 256 -> 18 channels at 4x4 (fp32) =============
__global__ __launch_bounds__(256)
void offconv_kernel(const ushort* __restrict__ hH, const ushort* __restrict__ hL,
                    const float* __restrict__ ow, const float* __restrict__ ob,
                    float* __restrict__ off)
{
    __shared__ float plane[256][36];
    int b = blockIdx.x, tid = threadIdx.x;
    for (int i = tid; i < 256 * 36; i += 256) (&plane[0][0])[i] = 0.f;
    __syncthreads();
    for (int i = tid; i < 4096; i += 256) {
        int px = i >> 8, c = i & 255;
        size_t idx = ((size_t)b * 16 + px) * 256 + c;
        plane[c][((px >> 2) + 1) * 6 + (px & 3) + 1] = b2f(hH[idx]) + b2f(hL[idx]);
    }
    __syncthreads();
    for (int o = tid; o < 288; o += 256) {
        int co = o >> 4, px = o & 15, y = px >> 2, x = px & 3;
        float s = ob[co];
        const float* wb = ow + (size_t)co * 256 * 9;
        for (int c = 0; c < 256; c++) {
            const float* wc = wb + c * 9;
            const float* pl = &plane[c][y * 6 + x];
#pragma unroll
            for (int r = 0; r < 3; r++)
#pragma unroll
                for (int k = 0; k < 3; k++)
                    s = fmaf(wc[r * 3 + k], pl[r * 6 + k], s);
        }
        off[((size_t)b * 18 + co) * 16 + px] = s;
    }
}

// ====== deformable sampling -> xo hi/lo bf16 planes [2048][2304] ===========
__global__ __launch_bounds__(256)
void sample_kernel(const ushort* __restrict__ hH, const ushort* __restrict__ hL,
                   const float* __restrict__ off, ushort* __restrict__ xoH,
                   ushort* __restrict__ xoL)
{
    __shared__ float plane[256][36];
    __shared__ int   tidx[144][4];
    __shared__ float twt[144][4];
    int b = blockIdx.x, tid = threadIdx.x;
    for (int i = tid; i < 256 * 36; i += 256) (&plane[0][0])[i] = 0.f;
    __syncthreads();
    for (int i = tid; i < 4096; i += 256) {
        int px = i >> 8, c = i & 255;
        size_t idx = ((size_t)b * 16 + px) * 256 + c;
        plane[c][((px >> 2) + 1) * 6 + (px & 3) + 1] = b2f(hH[idx]) + b2f(hL[idx]);
    }
    if (tid < 144) {
        int px = tid / 9, n = tid % 9;
        int y = px >> 2, x = px & 3;
        float ox_ = off[((size_t)b * 18 + 2 * n) * 16 + px];
        float oy_ = off[((size_t)b * 18 + 2 * n + 1) * 16 + px];
        float pxc = (float)(y + 1) + (float)(n / 3 - 1) + ox_;
        float pyc = (float)(x + 1) + (float)(n % 3 - 1) + oy_;
        if (pxc < 1.f || pxc > 4.f) pxc = floorf(pxc);
        if (pyc < 1.f || pyc > 4.f) pyc = floorf(pyc);
        pxc = fminf(fmaxf(pxc, 0.f), 5.f);
        pyc = fminf(fmaxf(pyc, 0.f), 5.f);
        float fx = floorf(pxc), fy = floorf(pyc);
        float qrbx = fminf(fx + 1.f, 5.f), qrby = fminf(fy + 1.f, 5.f);
        float wx_lt = 1.f + (fx - pxc), wx_rb = 1.f - (qrbx - pxc);
        float wy_lt = 1.f + (fy - pyc), wy_rb = 1.f - (qrby - pyc);
        tidx[tid][0] = (int)(fx * 6.f + fy);     twt[tid][0] = wx_lt * wy_lt;
        tidx[tid][1] = (int)(qrbx * 6.f + qrby); twt[tid][1] = wx_rb * wy_rb;
        tidx[tid][2] = (int)(fx * 6.f + qrby);   twt[tid][2] = wx_lt * wy_rb;
        tidx[tid][3] = (int)(qrbx * 6.f + fy);   twt[tid][3] = wx_rb * wy_lt;
    }
    __syncthreads();
    for (int s = tid; s < 36864; s += 256) {
        int px = s / 2304, k = s - px * 2304;
        int c = k / 9, n = k - c * 9;
        int t = px * 9 + n;
        const float* pc = plane[c];
        float v = twt[t][0] * pc[tidx[t][0]] + twt[t][1] * pc[tidx[t][1]] +
                  twt[t][2] * pc[tidx[t][2]] + twt[t][3] * pc[tidx[t][3]];
        ushort h = f2b(v);
        size_t o = ((size_t)b * 16 + px) * 2304 + k;
        xoH[o] = h;
        xoL[o] = f2b(v - b2f(h));
    }
}

// ============== bn5 stats over relu(dout fp32) =============================
__global__ __launch_bounds__(256)
void stats5_kernel(const float* __restrict__ dout, float* __restrict__ sum5,
                   float* __restrict__ sq5)
{
    __shared__ float rs[256], rq[256];
    int c = blockIdx.x, tid = threadIdx.x;
    float s = 0.f, q = 0.f;
    for (int i = tid; i < 2048; i += 256) {
        float v = fmaxf(dout[(size_t)i * 256 + c], 0.f);
        s += v; q += v * v;
    }
    rs[tid] = s; rq[tid] = q; __syncthreads();
    for (int st = 128; st > 0; st >>= 1) {
        if (tid < st) { rs[tid] += rs[tid + st]; rq[tid] += rq[tid + st]; }
        __syncthreads();
    }
    if (tid == 0) { sum5[c] = rs[0]; sq5[c] = rq[0]; }
}

// ====== head: relu -> bn5 folded into mean -> fc -> log_softmax ============
__global__ __launch_bounds__(256)
void final_kernel(const float* __restrict__ dout, const float* __restrict__ A5,
                  const float* __restrict__ B5, const float* __restrict__ fcw,
                  const float* __restrict__ fcb, float* __restrict__ out)
{
    __shared__ float hbar[256];
    __shared__ float red[256];
    int b = blockIdx.x, tid = threadIdx.x;
    float s = 0.f;
#pragma unroll 4
    for (int px = 0; px < 16; px++)
        s += fmaxf(dout[((size_t)b * 16 + px) * 256 + tid], 0.f);
    hbar[tid] = fmaf(A5[tid], s * (1.f / 16.f), B5[tid]);
    __syncthreads();
    float logit = -1e30f;
    if (tid < 250) {
        float acc = fcb[tid];
        const float4* wr = (const float4*)(fcw + (size_t)tid * 256);
        const float4* hv = (const float4*)hbar;
#pragma unroll 4
        for (int i = 0; i < 64; i++) {
            float4 w4 = wr[i], h4 = hv[i];
            acc = fmaf(w4.x, h4.x, acc); acc = fmaf(w4.y, h4.y, acc);
            acc = fmaf(w4.z, h4.z, acc); acc = fmaf(w4.w, h4.w, acc);
        }
        logit = acc;
    }
    red[tid] = logit; __syncthreads();
    for (int st = 128; st > 0; st >>= 1) {
        if (tid < st) red[tid] = fmaxf(red[tid], red[tid + st]);
        __syncthreads();
    }
    float mx = red[0]; __syncthreads();
    float e = (tid < 250) ? expf(logit - mx) : 0.f;
    red[tid] = e; __syncthreads();
    for (int st = 128; st > 0; st >>= 1) {
        if (tid < st) red[tid] += red[tid + st];
        __syncthreads();
    }
    float lse = logf(red[0]) + mx;
    if (tid < 250) out[(size_t)b * 250 + tid] = logit - lse;
}

// ===========================================================================
extern "C" void kernel_launch(void* const* d_in, const int* in_sizes, int n_in,
                              void* d_out, int out_size, void* d_ws, size_t ws_size,
                              hipStream_t stream)
{
    const float* s_in = (const float*)d_in[0];
    const float* c1w = (const float*)d_in[1];  const float* c1b = (const float*)d_in[2];
    const float* g1  = (const float*)d_in[3];  const float* b1  = (const float*)d_in[4];
    const float* c2w = (const float*)d_in[5];  const float* c2b = (const float*)d_in[6];
    const float* g2  = (const float*)d_in[7];  const float* b2  = (const float*)d_in[8];
    const float* c3w = (const float*)d_in[9];  const float* c3b = (const float*)d_in[10];
    const float* g3  = (const float*)d_in[11]; const float* b3  = (const float*)d_in[12];
    const float* c4w = (const float*)d_in[13]; const float* c4b = (const float*)d_in[14];
    const float* g4  = (const float*)d_in[15]; const float* b4  = (const float*)d_in[16];
    const float* ofw = (const float*)d_in[17]; const float* ofb = (const float*)d_in[18];
    const float* dcw = (const float*)d_in[19];
    const float* g5  = (const float*)d_in[20]; const float* b5  = (const float*)d_in[21];
    const float* fcw = (const float*)d_in[22]; const float* fcb = (const float*)d_in[23];

    float* ws   = (float*)d_ws;
    float* stat = ws;                       // 2560
    float* ab   = ws + 2560;                // 2560
    float* zpad = ws + 5120;                // 64
    ushort* w2h = (ushort*)(ws + 5184);     // 73728 u
    ushort* w2l = (ushort*)(ws + 42048);
    ushort* w3h = (ushort*)(ws + 78912);    // 294912 u
    ushort* w3l = (ushort*)(ws + 226368);
    ushort* w4h = (ushort*)(ws + 373824);   // 589824 u
    ushort* w4l = (ushort*)(ws + 668736);
    ushort* wdh = (ushort*)(ws + 963648);   // 589824 u
    ushort* wdl = (ushort*)(ws + 1258560);
    ushort* poolH = (ushort*)(ws + 1553472);  // 8,388,608 u max
    ushort* poolL = (ushort*)(ws + 5747776);
    float*  conv32 = ws + 9942080;            // 16,777,216 f max (reused below)
    ushort* xoH  = (ushort*)(ws + 9942080);   // 4,718,592 u
    ushort* xoL  = (ushort*)(ws + 12301376);
    float*  dout = ws + 14660672;             // 524,288 f
    float*  offb = ws + 15184960;             // 36,864 f

    hipMemsetAsync(stat, 0, 2048 * sizeof(float), stream);
    hipMemsetAsync(zpad, 0, 256, stream);

    // weight split-conversions
    wcvt_kernel<<<(128 * 64 * 9 + 255) / 256, 256, 0, stream>>>(c2w, w2h, w2l, 64, 1, 128 * 64 * 9);
    wcvt_kernel<<<(256 * 128 * 9 + 255) / 256, 256, 0, stream>>>(c3w, w3h, w3l, 128, 1, 256 * 128 * 9);
    wcvt_kernel<<<(256 * 256 * 9 + 255) / 256, 256, 0, stream>>>(c4w, w4h, w4l, 256, 1, 256 * 256 * 9);
    wcvt_kernel<<<(256 * 2304 + 255) / 256, 256, 0, stream>>>(dcw, wdh, wdl, 256, 0, 256 * 2304);

    // ---- stage 1: conv1 (recompute trick) -> hi/lo NHWC [B,32,32,64] ----
    conv1_kernel<1><<<dim3(512, 8), 256, 0, stream>>>(s_in, c1w, c1b, nullptr, nullptr,
                                                      stat, stat + 256, nullptr, nullptr);
    bn_finalize<<<1, 256, 0, stream>>>(stat, stat + 256, g1, b1, ab, ab + 256, 64,
                                       1.0f / (128.f * 64.f * 64.f));
    conv1_kernel<2><<<dim3(512, 8), 256, 0, stream>>>(s_in, c1w, c1b, poolH, poolL,
                                                      nullptr, nullptr, ab, ab + 256);

    // ---- stage 2: conv2 GEMM (M=131072, N=128, K=576) ----
    gemm_kernel<576, 64, 32, 32, 128, true, true, true><<<dim3(1024, 2), 256, 0, stream>>>(
        poolH, poolL, w2h, w2l, c2b, conv32, (const ushort*)zpad, stat + 512, stat + 768);
    bn_finalize<<<1, 256, 0, stream>>>(stat + 512, stat + 768, g2, b2, ab + 512, ab + 768,
                                       128, 1.0f / (128.f * 32.f * 32.f));
    bnpool_kernel<128, 32, 32><<<2048, 256, 0, stream>>>(conv32, ab + 512, ab + 768, poolH, poolL);

    // ---- stage 3: conv3 GEMM (M=32768, N=256, K=1152) ----
    gemm_kernel<1152, 128, 16, 16, 256, true, true, true><<<dim3(256, 4), 256, 0, stream>>>(
        poolH, poolL, w3h, w3l, c3b, conv32, (const ushort*)zpad, stat + 1024, stat + 1280);
    bn_finalize<<<1, 256, 0, stream>>>(stat + 1024, stat + 1280, g3, b3, ab + 1024, ab + 1280,
                                       256, 1.0f / (128.f * 16.f * 16.f));
    bnpool_kernel<256, 16, 16><<<1024, 256, 0, stream>>>(conv32, ab + 1024, ab + 1280, poolH, poolL);

    // ---- stage 4: conv4 GEMM (M=8192, N=256, K=2304) ----
    gemm_kernel<2304, 256, 8, 8, 256, true, true, true><<<dim3(64, 4), 256, 0, stream>>>(
        poolH, poolL, w4h, w4l, c4b, conv32, (const ushort*)zpad, stat + 1536, stat + 1792);
    bn_finalize<<<1, 256, 0, stream>>>(stat + 1536, stat + 1792, g4, b4, ab + 1536, ab + 1792,
                                       256, 1.0f / (128.f * 8.f * 8.f));
    bnpool_kernel<256, 8, 8><<<256, 256, 0, stream>>>(conv32, ab + 1536, ab + 1792, poolH, poolL);

    // ---- deformable conv ----
    offconv_kernel<<<128, 256, 0, stream>>>(poolH, poolL, ofw, ofb, offb);
    sample_kernel<<<128, 256, 0, stream>>>(poolH, poolL, offb, xoH, xoL);
    gemm_kernel<2304, 2304, 1, 1, 256, false, false, false><<<dim3(16, 4), 256, 0, stream>>>(
        xoH, xoL, wdh, wdl, nullptr, dout, (const ushort*)zpad, nullptr, nullptr);

    // ---- bn5 + head ----
    stats5_kernel<<<256, 256, 0, stream>>>(dout, stat + 2048, stat + 2304);
    bn_finalize<<<1, 256, 0, stream>>>(stat + 2048, stat + 2304, g5, b5, ab + 2048, ab + 2304,
                                       256, 1.0f / 2048.f);
    final_kernel<<<128, 256, 0, stream>>>(dout, ab + 2048, ab + 2304, fcw, fcb, (float*)d_out);
}

// Round 5
// 523.242 us; speedup vs baseline: 3.5616x; 1.0477x over previous
//
#include <hip/hip_runtime.h>
#include <math.h>

typedef float  f32x4 __attribute__((ext_vector_type(4)));
typedef short  s16x8 __attribute__((ext_vector_type(8)));

__device__ __forceinline__ float b2f(ushort u) { return __uint_as_float(((unsigned)u) << 16); }
__device__ __forceinline__ ushort f2b(float f) {
    unsigned u = __float_as_uint(f);
    return (ushort)((u + 0x7FFFu + ((u >> 16) & 1u)) >> 16);
}
__device__ __forceinline__ void gload16(const void* g, void* l) {
    __builtin_amdgcn_global_load_lds((const __attribute__((address_space(1))) void*)g,
                                     (__attribute__((address_space(3))) void*)l, 16, 0, 0);
}

// ====== weight convert: fp32 OIHW -> bf16 hi/lo planes [CO][ksp*CI+ci] =====
__global__ __launch_bounds__(256)
void wcvt_kernel(const float* __restrict__ src, ushort* __restrict__ dsth,
                 ushort* __restrict__ dstl, int CI, int reorder, int total)
{
    int i = blockIdx.x * 256 + threadIdx.x;
    if (i >= total) return;
    float v;
    if (reorder) {
        int k9 = CI * 9;
        int co = i / k9; int rem = i - co * k9;
        int ksp = rem / CI; int ci = rem - ksp * CI;
        v = src[(size_t)(co * CI + ci) * 9 + ksp];
    } else {
        v = src[i];
    }
    ushort h = f2b(v);
    dsth[i] = h;
    dstl[i] = f2b(v - b2f(h));
}

// ================= split-bf16 MFMA implicit-GEMM ===========================
// 3-buffer LDS pipeline, counted vmcnt (T3+T4): stage k+2 while computing k;
// wait vmcnt(6) (own 6 loads of tile k done, k+1 in flight) -> s_barrier.
// acc += ah*wh + al*wh + ah*wl. BM=128, BN=64, BK=32; 4 waves (2x2).
template<int KTOT, int CIN, int HH, int WW, int COUT, bool IM2COL, bool BIAS, bool STATS, int SPLITK>
__global__ __launch_bounds__(256)
void gemm_kernel(const ushort* __restrict__ inH, const ushort* __restrict__ inL,
                 const ushort* __restrict__ wbh, const ushort* __restrict__ wbl,
                 const float* __restrict__ bias, float* __restrict__ out,
                 const ushort* __restrict__ zsrc0,
                 float* __restrict__ gsum, float* __restrict__ gsq)
{
    constexpr int BUF = 24576;   // ah 8K | al 8K | bh 4K | bl 4K
    __shared__ union {
        char s[3 * BUF];
        float c[128][66];
    } u;
    __shared__ float blkstat[64][2];

    const int tid  = threadIdx.x;
    const int lane = tid & 63, wv = tid >> 6;
    const int lr = lane & 15, lg = lane >> 4;
    const int wm = wv >> 1,  wn = wv & 1;
    int gx = blockIdx.x;
    gx = (gx & 7) * (gridDim.x >> 3) + (gx >> 3);   // bijective XCD swizzle (grid.x % 8 == 0)
    const int m0 = gx * 128;
    const int n0 = blockIdx.y * 64;

    constexpr int NK  = KTOT / 32;
    constexpr int NKS = NK / SPLITK;
    const int kz = (SPLITK > 1) ? blockIdx.z : 0;
    const int kb = kz * NKS, ke = kb + NKS;
    float* obase = (SPLITK > 1)
        ? out + (size_t)kz * (size_t)gridDim.x * 128 * COUT : out;

    // ---- staging precompute (thread stages phys chunk sch of rows) ----
    const int sch = tid & 3;
    int aco[2], apix[2], ay[2] = {0,0}, ax[2] = {0,0};
#pragma unroll
    for (int q = 0; q < 2; q++) {
        int row = (tid >> 2) + q * 64;
        aco[q] = ((sch ^ ((row >> 1) & 3)) << 3);
        int m = m0 + row;
        apix[q] = m;
        if constexpr (IM2COL) {
            int rem = m & (HH * WW - 1);
            ay[q] = rem / WW;
            ax[q] = rem & (WW - 1);
        }
    }
    const int brow = tid >> 2;
    const size_t bbase = (size_t)(n0 + brow) * KTOT + ((sch ^ ((brow >> 1) & 3)) << 3);

    // ---- fragment read offsets (conflict-free, verified r4) ----
    const int chunk_p = (lg ^ ((lr >> 1) & 3)) << 4;
    int afoff[4], bfoff[2];
#pragma unroll
    for (int mi = 0; mi < 4; mi++) afoff[mi] = (wm * 64 + mi * 16 + lr) * 64 + chunk_p;
#pragma unroll
    for (int ni = 0; ni < 2; ni++) bfoff[ni] = 16384 + (wn * 32 + ni * 16 + lr) * 64 + chunk_p;

    float bv[2] = {0.f, 0.f};
    if (BIAS) { bv[0] = bias[n0 + wn * 32 + lr]; bv[1] = bias[n0 + wn * 32 + 16 + lr]; }

    f32x4 acc[4][2] = {};

    auto stage = [&](int kt, int buf) {
        char* dst = u.s + buf * BUF;
        char* dA = dst + wv * 1024;            // + q*4096; lane*16 added by HW
        char* dB = dst + 16384 + wv * 1024;
        if constexpr (IM2COL) {
            int ksp = (kt * 32) / CIN;
            int c0  = (kt * 32) & (CIN - 1);
            int d3  = ksp / 3;
            int dy = d3 - 1, dx = ksp - d3 * 3 - 1;
            int dpix = dy * WW + dx;
#pragma unroll
            for (int q = 0; q < 2; q++) {
                int iy = ay[q] + dy, ix = ax[q] + dx;
                bool ok = ((unsigned)iy < (unsigned)HH) && ((unsigned)ix < (unsigned)WW);
                size_t so = (size_t)(apix[q] + dpix) * CIN + c0 + aco[q];
                gload16(ok ? (const void*)(inH + so) : (const void*)(zsrc0 + aco[q]),
                        dA + q * 4096);
                gload16(ok ? (const void*)(inL + so) : (const void*)(zsrc0 + aco[q]),
                        dA + 8192 + q * 4096);
            }
        } else {
#pragma unroll
            for (int q = 0; q < 2; q++) {
                size_t so = (size_t)apix[q] * KTOT + kt * 32 + aco[q];
                gload16(inH + so, dA + q * 4096);
                gload16(inL + so, dA + 8192 + q * 4096);
            }
        }
        gload16(wbh + bbase + kt * 32, dB);
        gload16(wbl + bbase + kt * 32, dB + 4096);
    };

    // ---- prologue: 2 tiles in flight ----
    stage(kb, 0);
    stage(kb + 1, 1);
    int rslot = 0, wslot = 2;
#pragma unroll 1
    for (int kt = kb; kt < ke; kt++) {
        if (kt + 1 < ke) { asm volatile("s_waitcnt vmcnt(6)" ::: "memory"); }
        else             { asm volatile("s_waitcnt vmcnt(0)" ::: "memory"); }
        __builtin_amdgcn_s_barrier();
        __builtin_amdgcn_sched_barrier(0);
        if (kt + 2 < ke) stage(kt + 2, wslot);
        const char* base = u.s + rslot * BUF;
        s16x8 ah4[4], al4[4], bh2[2], bl2[2];
#pragma unroll
        for (int mi = 0; mi < 4; mi++) {
            ah4[mi] = *(const s16x8*)(base + afoff[mi]);
            al4[mi] = *(const s16x8*)(base + afoff[mi] + 8192);
        }
#pragma unroll
        for (int ni = 0; ni < 2; ni++) {
            bh2[ni] = *(const s16x8*)(base + bfoff[ni]);
            bl2[ni] = *(const s16x8*)(base + bfoff[ni] + 4096);
        }
        __builtin_amdgcn_s_setprio(1);
#pragma unroll
        for (int mi = 0; mi < 4; mi++)
#pragma unroll
            for (int ni = 0; ni < 2; ni++) {
                acc[mi][ni] = __builtin_amdgcn_mfma_f32_16x16x32_bf16(
                    ah4[mi], bh2[ni], acc[mi][ni], 0, 0, 0);
                acc[mi][ni] = __builtin_amdgcn_mfma_f32_16x16x32_bf16(
                    al4[mi], bh2[ni], acc[mi][ni], 0, 0, 0);
                acc[mi][ni] = __builtin_amdgcn_mfma_f32_16x16x32_bf16(
                    ah4[mi], bl2[ni], acc[mi][ni], 0, 0, 0);
            }
        __builtin_amdgcn_s_setprio(0);
        rslot = (rslot == 2) ? 0 : rslot + 1;
        wslot = (wslot == 2) ? 0 : wslot + 1;
    }
    __syncthreads();

    // ---- epilogue: bias, LDS transpose, fp32 store, fused BN stats ----
    if (STATS && tid < 128) ((float*)blkstat)[tid] = 0.f;
#pragma unroll
    for (int mi = 0; mi < 4; mi++)
#pragma unroll
        for (int ni = 0; ni < 2; ni++)
#pragma unroll
            for (int r = 0; r < 4; r++)
                u.c[wm * 64 + mi * 16 + lg * 4 + r][wn * 32 + ni * 16 + lr] = acc[mi][ni][r] + bv[ni];
    __syncthreads();

    const int chunk = tid & 7, rbase = tid >> 3;
    float ss[8] = {0,0,0,0,0,0,0,0}, qq[8] = {0,0,0,0,0,0,0,0};
#pragma unroll
    for (int i = 0; i < 4; i++) {
        int row = rbase + i * 32;
        float v[8];
#pragma unroll
        for (int j = 0; j < 8; j++) {
            v[j] = u.c[row][chunk * 8 + j];
            if (STATS) { ss[j] += v[j]; qq[j] += v[j] * v[j]; }
        }
        size_t base = (size_t)(m0 + row) * COUT + n0 + chunk * 8;
        *(float4*)&obase[base]     = make_float4(v[0], v[1], v[2], v[3]);
        *(float4*)&obase[base + 4] = make_float4(v[4], v[5], v[6], v[7]);
    }
    if (STATS) {
#pragma unroll
        for (int j = 0; j < 8; j++) {
            atomicAdd(&blkstat[chunk * 8 + j][0], ss[j]);
            atomicAdd(&blkstat[chunk * 8 + j][1], qq[j]);
        }
        __syncthreads();
        if (tid < 64) {
            atomicAdd(&gsum[n0 + tid], blkstat[tid][0]);
            atomicAdd(&gsq[n0 + tid],  blkstat[tid][1]);
        }
    }
}

// ============== sum 4 split-K parts (deterministic) ========================
__global__ __launch_bounds__(256)
void sum4_kernel(const float* __restrict__ parts, float* __restrict__ outd)
{
    int i = (blockIdx.x * 256 + threadIdx.x) * 4;   // 524288 / 4 = 131072 threads
    float4 a = *(const float4*)&parts[i];
    float4 b = *(const float4*)&parts[524288 + i];
    float4 c = *(const float4*)&parts[1048576 + i];
    float4 d = *(const float4*)&parts[1572864 + i];
    *(float4*)&outd[i] = make_float4(a.x + b.x + c.x + d.x, a.y + b.y + c.y + d.y,
                                     a.z + b.z + c.z + d.z, a.w + b.w + c.w + d.w);
}

// ================= BN finalize: A=g*rsqrt(var+eps), B=b-mu*A ===============
__global__ void bn_finalize(const float* __restrict__ sum, const float* __restrict__ sq,
                            const float* __restrict__ g, const float* __restrict__ b,
                            float* __restrict__ A, float* __restrict__ Bc,
                            int C, float invN)
{
    int c = threadIdx.x;
    if (c < C) {
        float mu  = sum[c] * invN;
        float var = sq[c] * invN - mu * mu;
        float s   = rsqrtf(var + 1e-5f) * g[c];
        A[c]  = s;
        Bc[c] = b[c] - mu * s;
    }
}

// ==== BN affine + relu + 2x2 maxpool (fp32 NHWC in -> hi/lo bf16 planes) ===
template<int CC, int HH, int WW>
__global__ __launch_bounds__(256)
void bnpool_kernel(const float* __restrict__ in, const float* __restrict__ A,
                   const float* __restrict__ Bc, ushort* __restrict__ outH,
                   ushort* __restrict__ outL)
{
    constexpr int CH = CC / 8, PW = WW / 2, PH = HH / 2;
    int i = blockIdx.x * 256 + threadIdx.x;
    int cc = i & (CH - 1);
    int t2 = i / CH;
    int px = t2 & (PW - 1);
    int t3 = t2 / PW;
    int py = t3 & (PH - 1);
    int b  = t3 / PH;
    const float* p = in + (size_t)((b * HH + 2 * py) * WW + 2 * px) * CC + cc * 8;
    float v00[8], v01[8], v10[8], v11[8];
#pragma unroll
    for (int j = 0; j < 8; j++) {
        v00[j] = p[j];
        v01[j] = p[CC + j];
        v10[j] = p[(size_t)WW * CC + j];
        v11[j] = p[(size_t)WW * CC + CC + j];
    }
    unsigned pwh[4], pwl[4];
#pragma unroll
    for (int jj = 0; jj < 4; jj++) {
        ushort h2[2], l2[2];
#pragma unroll
        for (int k = 0; k < 2; k++) {
            int j = jj * 2 + k;
            int c = cc * 8 + j;
            float Av = A[c], Bv = Bc[c];
            float m = fmaxf(fmaxf(fmaf(v00[j], Av, Bv), fmaf(v01[j], Av, Bv)),
                            fmaxf(fmaf(v10[j], Av, Bv), fmaf(v11[j], Av, Bv)));
            m = fmaxf(m, 0.f);
            h2[k] = f2b(m);
            l2[k] = f2b(m - b2f(h2[k]));
        }
        pwh[jj] = (unsigned)h2[0] | ((unsigned)h2[1] << 16);
        pwl[jj] = (unsigned)l2[0] | ((unsigned)l2[1] << 16);
    }
    *(uint4*)&outH[(size_t)i * 8] = make_uint4(pwh[0], pwh[1], pwh[2], pwh[3]);
    *(uint4*)&outL[(size_t)i * 8] = make_uint4(pwl[0], pwl[1], pwl[2], pwl[3]);
}

// ======== conv1 (1->64, 64x64, fp32): MODE1 stats / MODE2 pool->planes =====
template<int MODE>
__global__ __launch_bounds__(256)
void conv1_kernel(const float* __restrict__ in, const float* __restrict__ wgt,
                  const float* __restrict__ bias, ushort* __restrict__ outH,
                  ushort* __restrict__ outL,
                  float* __restrict__ ssum, float* __restrict__ ssq,
                  const float* __restrict__ bnA, const float* __restrict__ bnB)
{
    __shared__ float slab[34][34];
    __shared__ float redbuf[4 * 8 * 2];
    const int tid = threadIdx.x;
    const int bg = blockIdx.x >> 2, tile = blockIdx.x & 3;
    const int ty = (tile >> 1) * 32, tx = (tile & 1) * 32;
    const int cout0 = blockIdx.y * 8;
    const int qy = tid >> 4, qx = tid & 15;
    const int oy = ty + 2 * qy, ox = tx + 2 * qx;

    for (int idx = tid; idx < 34 * 34; idx += 256) {
        int sy = idx / 34, sx = idx - sy * 34;
        int gy = ty + sy - 1, gx = tx + sx - 1;
        float v = 0.f;
        if (gy >= 0 && gy < 64 && gx >= 0 && gx < 64)
            v = in[((size_t)bg * 64 + gy) * 64 + gx];
        (&slab[0][0])[idx] = v;
    }
    __syncthreads();
    float v[4][4];
#pragma unroll
    for (int r = 0; r < 4; r++) {
        float2 a = *(const float2*)&slab[2 * qy + r][2 * qx];
        float2 b = *(const float2*)&slab[2 * qy + r][2 * qx + 2];
        v[r][0] = a.x; v[r][1] = a.y; v[r][2] = b.x; v[r][3] = b.y;
    }
    float acc[4][8];
#pragma unroll
    for (int oc = 0; oc < 8; oc++) {
        const float* w9 = wgt + (size_t)(cout0 + oc) * 9;
        float w0 = w9[0], w1 = w9[1], w2 = w9[2], w3 = w9[3], w4 = w9[4],
              w5 = w9[5], w6 = w9[6], w7 = w9[7], w8 = w9[8];
        float bs = bias[cout0 + oc];
#pragma unroll
        for (int dy = 0; dy < 2; dy++)
#pragma unroll
            for (int dx = 0; dx < 2; dx++) {
                float s = bs;
                s = fmaf(w0, v[dy][dx], s);
                s = fmaf(w1, v[dy][dx + 1], s);
                s = fmaf(w2, v[dy][dx + 2], s);
                s = fmaf(w3, v[dy + 1][dx], s);
                s = fmaf(w4, v[dy + 1][dx + 1], s);
                s = fmaf(w5, v[dy + 1][dx + 2], s);
                s = fmaf(w6, v[dy + 2][dx], s);
                s = fmaf(w7, v[dy + 2][dx + 1], s);
                s = fmaf(w8, v[dy + 2][dx + 2], s);
                acc[dy * 2 + dx][oc] = s;
            }
    }
    if constexpr (MODE == 1) {
        int wave = tid >> 6, lanei = tid & 63;
#pragma unroll
        for (int oc = 0; oc < 8; oc++) {
            float s  = acc[0][oc] + acc[1][oc] + acc[2][oc] + acc[3][oc];
            float q2 = acc[0][oc] * acc[0][oc] + acc[1][oc] * acc[1][oc] +
                       acc[2][oc] * acc[2][oc] + acc[3][oc] * acc[3][oc];
#pragma unroll
            for (int off = 32; off > 0; off >>= 1) {
                s  += __shfl_down(s, off);
                q2 += __shfl_down(q2, off);
            }
            if (lanei == 0) {
                redbuf[(wave * 8 + oc) * 2 + 0] = s;
                redbuf[(wave * 8 + oc) * 2 + 1] = q2;
            }
        }
        __syncthreads();
        if (tid < 8) {
            float s = 0.f, q2 = 0.f;
#pragma unroll
            for (int w = 0; w < 4; w++) {
                s  += redbuf[(w * 8 + tid) * 2 + 0];
                q2 += redbuf[(w * 8 + tid) * 2 + 1];
            }
            atomicAdd(&ssum[cout0 + tid], s);
            atomicAdd(&ssq[cout0 + tid], q2);
        }
    }
    if constexpr (MODE == 2) {
        unsigned pwh[4], pwl[4];
#pragma unroll
        for (int jj = 0; jj < 4; jj++) {
            ushort h2[2], l2[2];
#pragma unroll
            for (int k = 0; k < 2; k++) {
                int oc = jj * 2 + k;
                float Av = bnA[cout0 + oc], Bv = bnB[cout0 + oc];
                float m0_ = fmaxf(fmaf(acc[0][oc], Av, Bv), fmaf(acc[1][oc], Av, Bv));
                float m1_ = fmaxf(fmaf(acc[2][oc], Av, Bv), fmaf(acc[3][oc], Av, Bv));
                float m = fmaxf(fmaxf(m0_, m1_), 0.f);
                h2[k] = f2b(m);
                l2[k] = f2b(m - b2f(h2[k]));
            }
            pwh[jj] = (unsigned)h2[0] | ((unsigned)h2[1] << 16);
            pwl[jj] = (unsigned)l2[0] | ((unsigned)l2[1] << 16);
        }
        size_t base = (size_t)((bg * 32 + (oy >> 1)) * 32 + (ox >> 1)) * 64 + cout0;
        *(uint4*)&outH[base] = make_uint4(pwh[0], pwh[1], pwh[2], pwh[3]);
        *(uint4*)&outL[base] = make_uint4(pwl[0], pwl[1], pwl[2], pwl[3]);
    }
}

// =============== offset conv: 256 -> 18 channels at 4x4 (fp32) =============
__global__ __launch_bounds__(256)
void offconv_kernel(const ushort* __restrict__ hH, const ushort* __restrict__ hL,
                    const float* __restrict__ ow, const float* __restrict__ ob,
                    float* __restrict__ off)
{
    __shared__ float plane[256][36];
    int b = blockIdx.x, tid = threadIdx.x;
    for (int i = tid; i < 256 * 36; i += 256) (&plane[0][0])[i] = 0.f;
    __syncthreads();
    for (int i = tid; i < 4096; i += 256) {
        int px = i >> 8, c = i & 255;
        size_t idx = ((size_t)b * 16 + px) * 256 + c;
        plane[c][((px >> 2) + 1) * 6 + (px & 3) + 1] = b2f(hH[idx]) + b2f(hL[idx]);
    }
    __syncthreads();
    for (int o = tid; o < 288; o += 256) {
        int co = o >> 4, px = o & 15, y = px >> 2, x = px & 3;
        float s = ob[co];
        const float* wb = ow + (size_t)co * 256 * 9;
        for (int c = 0; c < 256; c++) {
            const float* wc = wb + c * 9;
            const float* pl = &plane[c][y * 6 + x];
#pragma unroll
            for (int r = 0; r < 3; r++)
#pragma unroll
                for (int k = 0; k < 3; k++)
                    s = fmaf(wc[r * 3 + k], pl[r * 6 + k], s);
        }
        off[((size_t)b * 18 + co) * 16 + px] = s;
    }
}

// ====== deformable sampling -> xo hi/lo bf16 planes [2048][2304] ===========
__global__ __launch_bounds__(256)
void sample_kernel(const ushort* __restrict__ hH, const ushort* __restrict__ hL,
                   const float* __restrict__ off, ushort* __restrict__ xoH,
                   ushort* __restrict__ xoL)
{
    __shared__ float plane[256][36];
    __shared__ int   tidx[144][4];
    __shared__ float twt[144][4];
    int b = blockIdx.x, tid = threadIdx.x;
    for (int i = tid; i < 256 * 36; i += 256) (&plane[0][0])[i] = 0.f;
    __syncthreads();
    for (int i = tid; i < 4096; i += 256) {
        int px = i >> 8, c = i & 255;
        size_t idx = ((size_t)b * 16 + px) * 256 + c;
        plane[c][((px >> 2) + 1) * 6 + (px & 3) + 1] = b2f(hH[idx]) + b2f(hL[idx]);
    }
    if (tid < 144) {
        int px = tid / 9, n = tid % 9;
        int y = px >> 2, x = px & 3;
        float ox_ = off[((size_t)b * 18 + 2 * n) * 16 + px];
        float oy_ = off[((size_t)b * 18 + 2 * n + 1) * 16 + px];
        float pxc = (float)(y + 1) + (float)(n / 3 - 1) + ox_;
        float pyc = (float)(x + 1) + (float)(n % 3 - 1) + oy_;
        if (pxc < 1.f || pxc > 4.f) pxc = floorf(pxc);
        if (pyc < 1.f || pyc > 4.f) pyc = floorf(pyc);
        pxc = fminf(fmaxf(pxc, 0.f), 5.f);
        pyc = fminf(fmaxf(pyc, 0.f), 5.f);
        float fx = floorf(pxc), fy = floorf(pyc);
        float qrbx = fminf(fx + 1.f, 5.f), qrby = fminf(fy + 1.f, 5.f);
        float wx_lt = 1.f + (fx - pxc), wx_rb = 1.f - (qrbx - pxc);
        float wy_lt = 1.f + (fy - pyc), wy_rb = 1.f - (qrby - pyc);
        tidx[tid][0] = (int)(fx * 6.f + fy);     twt[tid][0] = wx_lt * wy_lt;
        tidx[tid][1] = (int)(qrbx * 6.f + qrby); twt[tid][1] = wx_rb * wy_rb;
        tidx[tid][2] = (int)(fx * 6.f + qrby);   twt[tid][2] = wx_lt * wy_rb;
        tidx[tid][3] = (int)(qrbx * 6.f + fy);   twt[tid][3] = wx_rb * wy_lt;
    }
    __syncthreads();
    for (int s = tid; s < 36864; s += 256) {
        int px = s / 2304, k = s - px * 2304;
        int c = k / 9, n = k - c * 9;
        int t = px * 9 + n;
        const float* pc = plane[c];
        float v = twt[t][0] * pc[tidx[t][0]] + twt[t][1] * pc[tidx[t][1]] +
                  twt[t][2] * pc[tidx[t][2]] + twt[t][3] * pc[tidx[t][3]];
        ushort h = f2b(v);
        size_t o = ((size_t)b * 16 + px) * 2304 + k;
        xoH[o] = h;
        xoL[o] = f2b(v - b2f(h));
    }
}

// ============== bn5 stats over relu(dout fp32) =============================
__global__ __launch_bounds__(256)
void stats5_kernel(const float* __restrict__ dout, float* __restrict__ sum5,
                   float* __restrict__ sq5)
{
    __shared__ float rs[256], rq[256];
    int c = blockIdx.x, tid = threadIdx.x;
    float s = 0.f, q = 0.f;
    for (int i = tid; i < 2048; i += 256) {
        float v = fmaxf(dout[(size_t)i * 256 + c], 0.f);
        s += v; q += v * v;
    }
    rs[tid] = s; rq[tid] = q; __syncthreads();
    for (int st = 128; st > 0; st >>= 1) {
        if (tid < st) { rs[tid] += rs[tid + st]; rq[tid] += rq[tid + st]; }
        __syncthreads();
    }
    if (tid == 0) { sum5[c] = rs[0]; sq5[c] = rq[0]; }
}

// ====== head: relu -> bn5 folded into mean -> fc -> log_softmax ============
__global__ __launch_bounds__(256)
void final_kernel(const float* __restrict__ dout, const float* __restrict__ A5,
                  const float* __restrict__ B5, const float* __restrict__ fcw,
                  const float* __restrict__ fcb, float* __restrict__ out)
{
    __shared__ float hbar[256];
    __shared__ float red[256];
    int b = blockIdx.x, tid = threadIdx.x;
    float s = 0.f;
#pragma unroll 4
    for (int px = 0; px < 16; px++)
        s += fmaxf(dout[((size_t)b * 16 + px) * 256 + tid], 0.f);
    hbar[tid] = fmaf(A5[tid], s * (1.f / 16.f), B5[tid]);
    __syncthreads();
    float logit = -1e30f;
    if (tid < 250) {
        float acc = fcb[tid];
        const float4* wr = (const float4*)(fcw + (size_t)tid * 256);
        const float4* hv = (const float4*)hbar;
#pragma unroll 4
        for (int i = 0; i < 64; i++) {
            float4 w4 = wr[i], h4 = hv[i];
            acc = fmaf(w4.x, h4.x, acc); acc = fmaf(w4.y, h4.y, acc);
            acc = fmaf(w4.z, h4.z, acc); acc = fmaf(w4.w, h4.w, acc);
        }
        logit = acc;
    }
    red[tid] = logit; __syncthreads();
    for (int st = 128; st > 0; st >>= 1) {
        if (tid < st) red[tid] = fmaxf(red[tid], red[tid + st]);
        __syncthreads();
    }
    float mx = red[0]; __syncthreads();
    float e = (tid < 250) ? expf(logit - mx) : 0.f;
    red[tid] = e; __syncthreads();
    for (int st = 128; st > 0; st >>= 1) {
        if (tid < st) red[tid] += red[tid + st];
        __syncthreads();
    }
    float lse = logf(red[0]) + mx;
    if (tid < 250) out[(size_t)b * 250 + tid] = logit - lse;
}

// ===========================================================================
extern "C" void kernel_launch(void* const* d_in, const int* in_sizes, int n_in,
                              void* d_out, int out_size, void* d_ws, size_t ws_size,
                              hipStream_t stream)
{
    const float* s_in = (const float*)d_in[0];
    const float* c1w = (const float*)d_in[1];  const float* c1b = (const float*)d_in[2];
    const float* g1  = (const float*)d_in[3];  const float* b1  = (const float*)d_in[4];
    const float* c2w = (const float*)d_in[5];  const float* c2b = (const float*)d_in[6];
    const float* g2  = (const float*)d_in[7];  const float* b2  = (const float*)d_in[8];
    const float* c3w = (const float*)d_in[9];  const float* c3b = (const float*)d_in[10];
    const float* g3  = (const float*)d_in[11]; const float* b3  = (const float*)d_in[12];
    const float* c4w = (const float*)d_in[13]; const float* c4b = (const float*)d_in[14];
    const float* g4  = (const float*)d_in[15]; const float* b4  = (const float*)d_in[16];
    const float* ofw = (const float*)d_in[17]; const float* ofb = (const float*)d_in[18];
    const float* dcw = (const float*)d_in[19];
    const float* g5  = (const float*)d_in[20]; const float* b5  = (const float*)d_in[21];
    const float* fcw = (const float*)d_in[22]; const float* fcb = (const float*)d_in[23];

    float* ws   = (float*)d_ws;
    float* stat = ws;                       // 2560
    float* ab   = ws + 2560;                // 2560
    float* zpad = ws + 5120;                // 64
    ushort* w2h = (ushort*)(ws + 5184);     // 73728 u
    ushort* w2l = (ushort*)(ws + 42048);
    ushort* w3h = (ushort*)(ws + 78912);    // 294912 u
    ushort* w3l = (ushort*)(ws + 226368);
    ushort* w4h = (ushort*)(ws + 373824);   // 589824 u
    ushort* w4l = (ushort*)(ws + 668736);
    ushort* wdh = (ushort*)(ws + 963648);   // 589824 u
    ushort* wdl = (ushort*)(ws + 1258560);
    ushort* poolH = (ushort*)(ws + 1553472);  // 8,388,608 u max
    ushort* poolL = (ushort*)(ws + 5747776);
    float*  conv32 = ws + 9942080;            // 16,777,216 f max (reused below)
    ushort* xoH  = (ushort*)(ws + 9942080);   // 4,718,592 u
    ushort* xoL  = (ushort*)(ws + 12301376);
    float*  dout = ws + 14660672;             // 524,288 f
    float*  offb = ws + 15184960;             // 36,864 f
    float*  dparts = ws + 15221824;           // 4 x 524,288 f

    hipMemsetAsync(stat, 0, 2048 * sizeof(float), stream);
    hipMemsetAsync(zpad, 0, 256, stream);

    // weight split-conversions
    wcvt_kernel<<<(128 * 64 * 9 + 255) / 256, 256, 0, stream>>>(c2w, w2h, w2l, 64, 1, 128 * 64 * 9);
    wcvt_kernel<<<(256 * 128 * 9 + 255) / 256, 256, 0, stream>>>(c3w, w3h, w3l, 128, 1, 256 * 128 * 9);
    wcvt_kernel<<<(256 * 256 * 9 + 255) / 256, 256, 0, stream>>>(c4w, w4h, w4l, 256, 1, 256 * 256 * 9);
    wcvt_kernel<<<(256 * 2304 + 255) / 256, 256, 0, stream>>>(dcw, wdh, wdl, 256, 0, 256 * 2304);

    // ---- stage 1: conv1 (recompute trick) -> hi/lo NHWC [B,32,32,64] ----
    conv1_kernel<1><<<dim3(512, 8), 256, 0, stream>>>(s_in, c1w, c1b, nullptr, nullptr,
                                                      stat, stat + 256, nullptr, nullptr);
    bn_finalize<<<1, 256, 0, stream>>>(stat, stat + 256, g1, b1, ab, ab + 256, 64,
                                       1.0f / (128.f * 64.f * 64.f));
    conv1_kernel<2><<<dim3(512, 8), 256, 0, stream>>>(s_in, c1w, c1b, poolH, poolL,
                                                      nullptr, nullptr, ab, ab + 256);

    // ---- stage 2: conv2 GEMM (M=131072, N=128, K=576) ----
    gemm_kernel<576, 64, 32, 32, 128, true, true, true, 1><<<dim3(1024, 2), 256, 0, stream>>>(
        poolH, poolL, w2h, w2l, c2b, conv32, (const ushort*)zpad, stat + 512, stat + 768);
    bn_finalize<<<1, 256, 0, stream>>>(stat + 512, stat + 768, g2, b2, ab + 512, ab + 768,
                                       128, 1.0f / (128.f * 32.f * 32.f));
    bnpool_kernel<128, 32, 32><<<2048, 256, 0, stream>>>(conv32, ab + 512, ab + 768, poolH, poolL);

    // ---- stage 3: conv3 GEMM (M=32768, N=256, K=1152) ----
    gemm_kernel<1152, 128, 16, 16, 256, true, true, true, 1><<<dim3(256, 4), 256, 0, stream>>>(
        poolH, poolL, w3h, w3l, c3b, conv32, (const ushort*)zpad, stat + 1024, stat + 1280);
    bn_finalize<<<1, 256, 0, stream>>>(stat + 1024, stat + 1280, g3, b3, ab + 1024, ab + 1280,
                                       256, 1.0f / (128.f * 16.f * 16.f));
    bnpool_kernel<256, 16, 16><<<1024, 256, 0, stream>>>(conv32, ab + 1024, ab + 1280, poolH, poolL);

    // ---- stage 4: conv4 GEMM (M=8192, N=256, K=2304) ----
    gemm_kernel<2304, 256, 8, 8, 256, true, true, true, 1><<<dim3(64, 4), 256, 0, stream>>>(
        poolH, poolL, w4h, w4l, c4b, conv32, (const ushort*)zpad, stat + 1536, stat + 1792);
    bn_finalize<<<1, 256, 0, stream>>>(stat + 1536, stat + 1792, g4, b4, ab + 1536, ab + 1792,
                                       256, 1.0f / (128.f * 8.f * 8.f));
    bnpool_kernel<256, 8, 8><<<256, 256, 0, stream>>>(conv32, ab + 1536, ab + 1792, poolH, poolL);

    // ---- deformable conv ----
    offconv_kernel<<<128, 256, 0, stream>>>(poolH, poolL, ofw, ofb, offb);
    sample_kernel<<<128, 256, 0, stream>>>(poolH, poolL, offb, xoH, xoL);
    gemm_kernel<2304, 2304, 1, 1, 256, false, false, false, 4><<<dim3(16, 4, 4), 256, 0, stream>>>(
        xoH, xoL, wdh, wdl, nullptr, dparts, (const ushort*)zpad, nullptr, nullptr);
    sum4_kernel<<<512, 256, 0, stream>>>(dparts, dout);

    // ---- bn5 + head ----
    stats5_kernel<<<256, 256, 0, stream>>>(dout, stat + 2048, stat + 2304);
    bn_finalize<<<1, 256, 0, stream>>>(stat + 2048, stat + 2304, g5, b5, ab + 2048, ab + 2304,
                                       256, 1.0f / 2048.f);
    final_kernel<<<128, 256, 0, stream>>>(dout, ab + 2048, ab + 2304, fcw, fcb, (float*)d_out);
}

// Round 6
// 455.258 us; speedup vs baseline: 4.0934x; 1.1493x over previous
//
#include <hip/hip_runtime.h>
#include <math.h>

typedef float  f32x4 __attribute__((ext_vector_type(4)));
typedef short  s16x8 __attribute__((ext_vector_type(8)));

__device__ __forceinline__ float b2f(ushort u) { return __uint_as_float(((unsigned)u) << 16); }
__device__ __forceinline__ ushort f2b(float f) {
    unsigned u = __float_as_uint(f);
    return (ushort)((u + 0x7FFFu + ((u >> 16) & 1u)) >> 16);
}
__device__ __forceinline__ void gload16(const void* g, void* l) {
    __builtin_amdgcn_global_load_lds((const __attribute__((address_space(1))) void*)g,
                                     (__attribute__((address_space(3))) void*)l, 16, 0, 0);
}

// ====== weight convert: fp32 OIHW -> bf16 hi/lo planes [CO][ksp*CI+ci] =====
__global__ __launch_bounds__(256)
void wcvt_kernel(const float* __restrict__ src, ushort* __restrict__ dsth,
                 ushort* __restrict__ dstl, int CI, int reorder, int total)
{
    int i = blockIdx.x * 256 + threadIdx.x;
    if (i >= total) return;
    float v;
    if (reorder) {
        int k9 = CI * 9;
        int co = i / k9; int rem = i - co * k9;
        int ksp = rem / CI; int ci = rem - ksp * CI;
        v = src[(size_t)(co * CI + ci) * 9 + ksp];
    } else {
        v = src[i];
    }
    ushort h = f2b(v);
    dsth[i] = h;
    dstl[i] = f2b(v - b2f(h));
}

// ================= split-bf16 MFMA implicit-GEMM ===========================
// 2-buffer stage-ahead (r4-proven), BM=128, BN=NB(64/128), BK=32; 4 waves 2x2,
// wave tile 64 x NB/2. acc += ah*wh + al*wh + ah*wl (error ~2^-18).
template<int KTOT, int CIN, int HH, int WW, int COUT, bool IM2COL, bool BIAS,
         bool STATS, int SPLITK, int NB>
__global__ __launch_bounds__(256)
void gemm_kernel(const ushort* __restrict__ inH, const ushort* __restrict__ inL,
                 const ushort* __restrict__ wbh, const ushort* __restrict__ wbl,
                 const float* __restrict__ bias, float* __restrict__ out,
                 const ushort* __restrict__ zsrc0,
                 float* __restrict__ gsum, float* __restrict__ gsq)
{
    constexpr int BUF = 16384 + NB * 128;   // ah 8K | al 8K | bh NB*64 | bl NB*64
    constexpr int NI  = NB / 32;            // B frags per wave
    constexpr int BQ  = NB / 64;            // B rows staged per thread
    __shared__ union {
        char s[2 * BUF];
        float c[128][NB + 4];
    } u;
    __shared__ float blkstat[NB][2];

    const int tid  = threadIdx.x;
    const int lane = tid & 63, wv = tid >> 6;
    const int lr = lane & 15, lg = lane >> 4;
    const int wm = wv >> 1,  wn = wv & 1;
    int gx = blockIdx.x;
    gx = (gx & 7) * (gridDim.x >> 3) + (gx >> 3);   // bijective XCD swizzle (grid.x % 8 == 0)
    const int m0 = gx * 128;
    const int n0 = blockIdx.y * NB;

    constexpr int NK  = KTOT / 32;
    constexpr int NKS = NK / SPLITK;
    const int kz = (SPLITK > 1) ? blockIdx.z : 0;
    const int kb = kz * NKS, ke = kb + NKS;
    float* obase = (SPLITK > 1)
        ? out + (size_t)kz * (size_t)gridDim.x * 128 * COUT : out;

    // ---- staging precompute ----
    const int sch = tid & 3;
    int aco[2], apix[2], ay[2] = {0,0}, ax[2] = {0,0};
#pragma unroll
    for (int q = 0; q < 2; q++) {
        int row = (tid >> 2) + q * 64;
        aco[q] = ((sch ^ ((row >> 1) & 3)) << 3);
        int m = m0 + row;
        apix[q] = m;
        if constexpr (IM2COL) {
            int rem = m & (HH * WW - 1);
            ay[q] = rem / WW;
            ax[q] = rem & (WW - 1);
        }
    }
    size_t bbase[BQ];
#pragma unroll
    for (int q = 0; q < BQ; q++) {
        int brow = (tid >> 2) + q * 64;
        bbase[q] = (size_t)(n0 + brow) * KTOT + ((sch ^ ((brow >> 1) & 3)) << 3);
    }

    // ---- fragment read offsets (conflict-free swizzle, verified r4) ----
    const int chunk_p = (lg ^ ((lr >> 1) & 3)) << 4;
    int afoff[4], bfoff[NI];
#pragma unroll
    for (int mi = 0; mi < 4; mi++) afoff[mi] = (wm * 64 + mi * 16 + lr) * 64 + chunk_p;
#pragma unroll
    for (int ni = 0; ni < NI; ni++)
        bfoff[ni] = 16384 + (wn * (NB / 2) + ni * 16 + lr) * 64 + chunk_p;

    float bv[NI];
#pragma unroll
    for (int ni = 0; ni < NI; ni++)
        bv[ni] = BIAS ? bias[n0 + wn * (NB / 2) + ni * 16 + lr] : 0.f;

    f32x4 acc[4][NI] = {};

    auto stage = [&](int kt, int buf) {
        char* dst = u.s + buf * BUF;
        char* dA = dst + wv * 1024;            // + q*4096; lane*16 added by HW
        char* dB = dst + 16384 + wv * 1024;
        if constexpr (IM2COL) {
            int ksp = (kt * 32) / CIN;
            int c0  = (kt * 32) & (CIN - 1);
            int d3  = ksp / 3;
            int dy = d3 - 1, dx = ksp - d3 * 3 - 1;
            int dpix = dy * WW + dx;
#pragma unroll
            for (int q = 0; q < 2; q++) {
                int iy = ay[q] + dy, ix = ax[q] + dx;
                bool ok = ((unsigned)iy < (unsigned)HH) && ((unsigned)ix < (unsigned)WW);
                size_t so = (size_t)(apix[q] + dpix) * CIN + c0 + aco[q];
                gload16(ok ? (const void*)(inH + so) : (const void*)(zsrc0 + aco[q]),
                        dA + q * 4096);
                gload16(ok ? (const void*)(inL + so) : (const void*)(zsrc0 + aco[q]),
                        dA + 8192 + q * 4096);
            }
        } else {
#pragma unroll
            for (int q = 0; q < 2; q++) {
                size_t so = (size_t)apix[q] * KTOT + kt * 32 + aco[q];
                gload16(inH + so, dA + q * 4096);
                gload16(inL + so, dA + 8192 + q * 4096);
            }
        }
#pragma unroll
        for (int q = 0; q < BQ; q++) {
            gload16(wbh + bbase[q] + kt * 32, dB + q * 4096);
            gload16(wbl + bbase[q] + kt * 32, dB + NB * 64 + q * 4096);
        }
    };

    stage(kb, 0);
    __syncthreads();
    int cur = 0;
#pragma unroll 1
    for (int kt = kb; kt < ke; kt++) {
        if (kt + 1 < ke) stage(kt + 1, cur ^ 1);
        const char* base = u.s + cur * BUF;
        s16x8 ah4[4], al4[4], bh2[NI], bl2[NI];
#pragma unroll
        for (int mi = 0; mi < 4; mi++) {
            ah4[mi] = *(const s16x8*)(base + afoff[mi]);
            al4[mi] = *(const s16x8*)(base + afoff[mi] + 8192);
        }
#pragma unroll
        for (int ni = 0; ni < NI; ni++) {
            bh2[ni] = *(const s16x8*)(base + bfoff[ni]);
            bl2[ni] = *(const s16x8*)(base + bfoff[ni] + NB * 64);
        }
        __builtin_amdgcn_s_setprio(1);
#pragma unroll
        for (int mi = 0; mi < 4; mi++)
#pragma unroll
            for (int ni = 0; ni < NI; ni++) {
                acc[mi][ni] = __builtin_amdgcn_mfma_f32_16x16x32_bf16(
                    ah4[mi], bh2[ni], acc[mi][ni], 0, 0, 0);
                acc[mi][ni] = __builtin_amdgcn_mfma_f32_16x16x32_bf16(
                    al4[mi], bh2[ni], acc[mi][ni], 0, 0, 0);
                acc[mi][ni] = __builtin_amdgcn_mfma_f32_16x16x32_bf16(
                    ah4[mi], bl2[ni], acc[mi][ni], 0, 0, 0);
            }
        __builtin_amdgcn_s_setprio(0);
        __syncthreads();   // drains next-tile loads (covered by the 48-MFMA phase) + WAR
        cur ^= 1;
    }

    // ---- epilogue: bias, LDS transpose, fp32 store, fused BN stats ----
    if (STATS && tid < NB * 2) ((float*)blkstat)[tid] = 0.f;
#pragma unroll
    for (int mi = 0; mi < 4; mi++)
#pragma unroll
        for (int ni = 0; ni < NI; ni++)
#pragma unroll
            for (int r = 0; r < 4; r++)
                u.c[wm * 64 + mi * 16 + lg * 4 + r][wn * (NB / 2) + ni * 16 + lr] =
                    acc[mi][ni][r] + bv[ni];
    __syncthreads();

    constexpr int NCH = NB / 8;        // 8-float chunks per row
    constexpr int RPI = 256 / NCH;     // rows per iteration
    constexpr int ITER = 128 / RPI;
    const int chunk = tid & (NCH - 1), rb = tid / NCH;
    float ss[8] = {0,0,0,0,0,0,0,0}, qq[8] = {0,0,0,0,0,0,0,0};
#pragma unroll
    for (int i = 0; i < ITER; i++) {
        int row = rb + i * RPI;
        float v[8];
#pragma unroll
        for (int j = 0; j < 8; j++) {
            v[j] = u.c[row][chunk * 8 + j];
            if (STATS) { ss[j] += v[j]; qq[j] += v[j] * v[j]; }
        }
        size_t base = (size_t)(m0 + row) * COUT + n0 + chunk * 8;
        *(float4*)&obase[base]     = make_float4(v[0], v[1], v[2], v[3]);
        *(float4*)&obase[base + 4] = make_float4(v[4], v[5], v[6], v[7]);
    }
    if (STATS) {
#pragma unroll
        for (int j = 0; j < 8; j++) {
            atomicAdd(&blkstat[chunk * 8 + j][0], ss[j]);
            atomicAdd(&blkstat[chunk * 8 + j][1], qq[j]);
        }
        __syncthreads();
        if (tid < NB) {
            atomicAdd(&gsum[n0 + tid], blkstat[tid][0]);
            atomicAdd(&gsq[n0 + tid],  blkstat[tid][1]);
        }
    }
}

// ====== sum P split-K parts (+bias, +BN stats), COUT=256, 8 rows/block =====
template<int P, bool BIASF, bool STATSF>
__global__ __launch_bounds__(256)
void sumk_kernel(const float* __restrict__ parts, size_t pstride,
                 const float* __restrict__ bias, float* __restrict__ outp,
                 float* __restrict__ gsum, float* __restrict__ gsq)
{
    __shared__ float bst[256][2];
    int tid = threadIdx.x;
    if (STATSF) { bst[tid][0] = 0.f; bst[tid][1] = 0.f; __syncthreads(); }
    size_t row = (size_t)blockIdx.x * 8 + (tid >> 5);
    int c0 = (tid & 31) * 8;
    size_t base = row * 256 + c0;
    float v[8];
    float4 a0 = *(const float4*)&parts[base];
    float4 a1 = *(const float4*)&parts[base + 4];
    v[0] = a0.x; v[1] = a0.y; v[2] = a0.z; v[3] = a0.w;
    v[4] = a1.x; v[5] = a1.y; v[6] = a1.z; v[7] = a1.w;
#pragma unroll
    for (int p = 1; p < P; p++) {
        float4 b0 = *(const float4*)&parts[p * pstride + base];
        float4 b1 = *(const float4*)&parts[p * pstride + base + 4];
        v[0] += b0.x; v[1] += b0.y; v[2] += b0.z; v[3] += b0.w;
        v[4] += b1.x; v[5] += b1.y; v[6] += b1.z; v[7] += b1.w;
    }
    if (BIASF) {
#pragma unroll
        for (int j = 0; j < 8; j++) v[j] += bias[c0 + j];
    }
    *(float4*)&outp[base]     = make_float4(v[0], v[1], v[2], v[3]);
    *(float4*)&outp[base + 4] = make_float4(v[4], v[5], v[6], v[7]);
    if (STATSF) {
#pragma unroll
        for (int j = 0; j < 8; j++) {
            atomicAdd(&bst[c0 + j][0], v[j]);
            atomicAdd(&bst[c0 + j][1], v[j] * v[j]);
        }
        __syncthreads();
        atomicAdd(&gsum[tid], bst[tid][0]);
        atomicAdd(&gsq[tid],  bst[tid][1]);
    }
}

// ================= BN finalize: A=g*rsqrt(var+eps), B=b-mu*A ===============
__global__ void bn_finalize(const float* __restrict__ sum, const float* __restrict__ sq,
                            const float* __restrict__ g, const float* __restrict__ b,
                            float* __restrict__ A, float* __restrict__ Bc,
                            int C, float invN)
{
    int c = threadIdx.x;
    if (c < C) {
        float mu  = sum[c] * invN;
        float var = sq[c] * invN - mu * mu;
        float s   = rsqrtf(var + 1e-5f) * g[c];
        A[c]  = s;
        Bc[c] = b[c] - mu * s;
    }
}

// ==== BN affine + relu + 2x2 maxpool (fp32 NHWC in -> hi/lo bf16 planes) ===
template<int CC, int HH, int WW>
__global__ __launch_bounds__(256)
void bnpool_kernel(const float* __restrict__ in, const float* __restrict__ A,
                   const float* __restrict__ Bc, ushort* __restrict__ outH,
                   ushort* __restrict__ outL)
{
    constexpr int CH = CC / 8, PW = WW / 2, PH = HH / 2;
    int i = blockIdx.x * 256 + threadIdx.x;
    int cc = i & (CH - 1);
    int t2 = i / CH;
    int px = t2 & (PW - 1);
    int t3 = t2 / PW;
    int py = t3 & (PH - 1);
    int b  = t3 / PH;
    const float* p = in + (size_t)((b * HH + 2 * py) * WW + 2 * px) * CC + cc * 8;
    float v00[8], v01[8], v10[8], v11[8];
#pragma unroll
    for (int j = 0; j < 8; j++) {
        v00[j] = p[j];
        v01[j] = p[CC + j];
        v10[j] = p[(size_t)WW * CC + j];
        v11[j] = p[(size_t)WW * CC + CC + j];
    }
    unsigned pwh[4], pwl[4];
#pragma unroll
    for (int jj = 0; jj < 4; jj++) {
        ushort h2[2], l2[2];
#pragma unroll
        for (int k = 0; k < 2; k++) {
            int j = jj * 2 + k;
            int c = cc * 8 + j;
            float Av = A[c], Bv = Bc[c];
            float m = fmaxf(fmaxf(fmaf(v00[j], Av, Bv), fmaf(v01[j], Av, Bv)),
                            fmaxf(fmaf(v10[j], Av, Bv), fmaf(v11[j], Av, Bv)));
            m = fmaxf(m, 0.f);
            h2[k] = f2b(m);
            l2[k] = f2b(m - b2f(h2[k]));
        }
        pwh[jj] = (unsigned)h2[0] | ((unsigned)h2[1] << 16);
        pwl[jj] = (unsigned)l2[0] | ((unsigned)l2[1] << 16);
    }
    *(uint4*)&outH[(size_t)i * 8] = make_uint4(pwh[0], pwh[1], pwh[2], pwh[3]);
    *(uint4*)&outL[(size_t)i * 8] = make_uint4(pwl[0], pwl[1], pwl[2], pwl[3]);
}

// ======== conv1 (1->64, 64x64, fp32): MODE1 stats / MODE2 pool->planes =====
template<int MODE>
__global__ __launch_bounds__(256)
void conv1_kernel(const float* __restrict__ in, const float* __restrict__ wgt,
                  const float* __restrict__ bias, ushort* __restrict__ outH,
                  ushort* __restrict__ outL,
                  float* __restrict__ ssum, float* __restrict__ ssq,
                  const float* __restrict__ bnA, const float* __restrict__ bnB)
{
    __shared__ float slab[34][34];
    __shared__ float redbuf[4 * 8 * 2];
    const int tid = threadIdx.x;
    const int bg = blockIdx.x >> 2, tile = blockIdx.x & 3;
    const int ty = (tile >> 1) * 32, tx = (tile & 1) * 32;
    const int cout0 = blockIdx.y * 8;
    const int qy = tid >> 4, qx = tid & 15;
    const int oy = ty + 2 * qy, ox = tx + 2 * qx;

    for (int idx = tid; idx < 34 * 34; idx += 256) {
        int sy = idx / 34, sx = idx - sy * 34;
        int gy = ty + sy - 1, gx = tx + sx - 1;
        float v = 0.f;
        if (gy >= 0 && gy < 64 && gx >= 0 && gx < 64)
            v = in[((size_t)bg * 64 + gy) * 64 + gx];
        (&slab[0][0])[idx] = v;
    }
    __syncthreads();
    float v[4][4];
#pragma unroll
    for (int r = 0; r < 4; r++) {
        float2 a = *(const float2*)&slab[2 * qy + r][2 * qx];
        float2 b = *(const float2*)&slab[2 * qy + r][2 * qx + 2];
        v[r][0] = a.x; v[r][1] = a.y; v[r][2] = b.x; v[r][3] = b.y;
    }
    float acc[4][8];
#pragma unroll
    for (int oc = 0; oc < 8; oc++) {
        const float* w9 = wgt + (size_t)(cout0 + oc) * 9;
        float w0 = w9[0], w1 = w9[1], w2 = w9[2], w3 = w9[3], w4 = w9[4],
              w5 = w9[5], w6 = w9[6], w7 = w9[7], w8 = w9[8];
        float bs = bias[cout0 + oc];
#pragma unroll
        for (int dy = 0; dy < 2; dy++)
#pragma unroll
            for (int dx = 0; dx < 2; dx++) {
                float s = bs;
                s = fmaf(w0, v[dy][dx], s);
                s = fmaf(w1, v[dy][dx + 1], s);
                s = fmaf(w2, v[dy][dx + 2], s);
                s = fmaf(w3, v[dy + 1][dx], s);
                s = fmaf(w4, v[dy + 1][dx + 1], s);
                s = fmaf(w5, v[dy + 1][dx + 2], s);
                s = fmaf(w6, v[dy + 2][dx], s);
                s = fmaf(w7, v[dy + 2][dx + 1], s);
                s = fmaf(w8, v[dy + 2][dx + 2], s);
                acc[dy * 2 + dx][oc] = s;
            }
    }
    if constexpr (MODE == 1) {
        int wave = tid >> 6, lanei = tid & 63;
#pragma unroll
        for (int oc = 0; oc < 8; oc++) {
            float s  = acc[0][oc] + acc[1][oc] + acc[2][oc] + acc[3][oc];
            float q2 = acc[0][oc] * acc[0][oc] + acc[1][oc] * acc[1][oc] +
                       acc[2][oc] * acc[2][oc] + acc[3][oc] * acc[3][oc];
#pragma unroll
            for (int off = 32; off > 0; off >>= 1) {
                s  += __shfl_down(s, off);
                q2 += __shfl_down(q2, off);
            }
            if (lanei == 0) {
                redbuf[(wave * 8 + oc) * 2 + 0] = s;
                redbuf[(wave * 8 + oc) * 2 + 1] = q2;
            }
        }
        __syncthreads();
        if (tid < 8) {
            float s = 0.f, q2 = 0.f;
#pragma unroll
            for (int w = 0; w < 4; w++) {
                s  += redbuf[(w * 8 + tid) * 2 + 0];
                q2 += redbuf[(w * 8 + tid) * 2 + 1];
            }
            atomicAdd(&ssum[cout0 + tid], s);
            atomicAdd(&ssq[cout0 + tid], q2);
        }
    }
    if constexpr (MODE == 2) {
        unsigned pwh[4], pwl[4];
#pragma unroll
        for (int jj = 0; jj < 4; jj++) {
            ushort h2[2], l2[2];
#pragma unroll
            for (int k = 0; k < 2; k++) {
                int oc = jj * 2 + k;
                float Av = bnA[cout0 + oc], Bv = bnB[cout0 + oc];
                float m0_ = fmaxf(fmaf(acc[0][oc], Av, Bv), fmaf(acc[1][oc], Av, Bv));
                float m1_ = fmaxf(fmaf(acc[2][oc], Av, Bv), fmaf(acc[3][oc], Av, Bv));
                float m = fmaxf(fmaxf(m0_, m1_), 0.f);
                h2[k] = f2b(m);
                l2[k] = f2b(m - b2f(h2[k]));
            }
            pwh[jj] = (unsigned)h2[0] | ((unsigned)h2[1] << 16);
            pwl[jj] = (unsigned)l2[0] | ((unsigned)l2[1] << 16);
        }
        size_t base = (size_t)((bg * 32 + (oy >> 1)) * 32 + (ox >> 1)) * 64 + cout0;
        *(uint4*)&outH[base] = make_uint4(pwh[0], pwh[1], pwh[2], pwh[3]);
        *(uint4*)&outL[base] = make_uint4(pwl[0], pwl[1], pwl[2], pwl[3]);
    }
}

// =============== offset conv: 256 -> 18 channels at 4x4 (fp32) =============
__global__ __launch_bounds__(256)
void offconv_kernel(const ushort* __restrict__ hH, const ushort* __restrict__ hL,
                    const float* __restrict__ ow, const float* __restrict__ ob,
                    float* __restrict__ off)
{
    __shared__ float plane[256][36];
    int b = blockIdx.x, tid = threadIdx.x;
    for (int i = tid; i < 256 * 36; i += 256) (&plane[0][0])[i] = 0.f;
    __syncthreads();
    for (int i = tid; i < 4096; i += 256) {
        int px = i >> 8, c = i & 255;
        size_t idx = ((size_t)b * 16 + px) * 256 + c;
        plane[c][((px >> 2) + 1) * 6 + (px & 3) + 1] = b2f(hH[idx]) + b2f(hL[idx]);
    }
    __syncthreads();
    for (int o = tid; o < 288; o += 256) {
        int co = o >> 4, px = o & 15, y = px >> 2, x = px & 3;
        float s = ob[co];
        const float* wb = ow + (size_t)co * 256 * 9;
        for (int c = 0; c < 256; c++) {
            const float* wc = wb + c * 9;
            const float* pl = &plane[c][y * 6 + x];
#pragma unroll
            for (int r = 0; r < 3; r++)
#pragma unroll
                for (int k = 0; k < 3; k++)
                    s = fmaf(wc[r * 3 + k], pl[r * 6 + k], s);
        }
        off[((size_t)b * 18 + co) * 16 + px] = s;
    }
}

// ====== deformable sampling -> xo hi/lo bf16 planes [2048][2304] ===========
__global__ __launch_bounds__(256)
void sample_kernel(const ushort* __restrict__ hH, const ushort* __restrict__ hL,
                   const float* __restrict__ off, ushort* __restrict__ xoH,
                   ushort* __restrict__ xoL)
{
    __shared__ float plane[256][36];
    __shared__ int   tidx[144][4];
    __shared__ float twt[144][4];
    int b = blockIdx.x, tid = threadIdx.x;
    for (int i = tid; i < 256 * 36; i += 256) (&plane[0][0])[i] = 0.f;
    __syncthreads();
    for (int i = tid; i < 4096; i += 256) {
        int px = i >> 8, c = i & 255;
        size_t idx = ((size_t)b * 16 + px) * 256 + c;
        plane[c][((px >> 2) + 1) * 6 + (px & 3) + 1] = b2f(hH[idx]) + b2f(hL[idx]);
    }
    if (tid < 144) {
        int px = tid / 9, n = tid % 9;
        int y = px >> 2, x = px & 3;
        float ox_ = off[((size_t)b * 18 + 2 * n) * 16 + px];
        float oy_ = off[((size_t)b * 18 + 2 * n + 1) * 16 + px];
        float pxc = (float)(y + 1) + (float)(n / 3 - 1) + ox_;
        float pyc = (float)(x + 1) + (float)(n % 3 - 1) + oy_;
        if (pxc < 1.f || pxc > 4.f) pxc = floorf(pxc);
        if (pyc < 1.f || pyc > 4.f) pyc = floorf(pyc);
        pxc = fminf(fmaxf(pxc, 0.f), 5.f);
        pyc = fminf(fmaxf(pyc, 0.f), 5.f);
        float fx = floorf(pxc), fy = floorf(pyc);
        float qrbx = fminf(fx + 1.f, 5.f), qrby = fminf(fy + 1.f, 5.f);
        float wx_lt = 1.f + (fx - pxc), wx_rb = 1.f - (qrbx - pxc);
        float wy_lt = 1.f + (fy - pyc), wy_rb = 1.f - (qrby - pyc);
        tidx[tid][0] = (int)(fx * 6.f + fy);     twt[tid][0] = wx_lt * wy_lt;
        tidx[tid][1] = (int)(qrbx * 6.f + qrby); twt[tid][1] = wx_rb * wy_rb;
        tidx[tid][2] = (int)(fx * 6.f + qrby);   twt[tid][2] = wx_lt * wy_rb;
        tidx[tid][3] = (int)(qrbx * 6.f + fy);   twt[tid][3] = wx_rb * wy_lt;
    }
    __syncthreads();
    for (int s = tid; s < 36864; s += 256) {
        int px = s / 2304, k = s - px * 2304;
        int c = k / 9, n = k - c * 9;
        int t = px * 9 + n;
        const float* pc = plane[c];
        float v = twt[t][0] * pc[tidx[t][0]] + twt[t][1] * pc[tidx[t][1]] +
                  twt[t][2] * pc[tidx[t][2]] + twt[t][3] * pc[tidx[t][3]];
        ushort h = f2b(v);
        size_t o = ((size_t)b * 16 + px) * 2304 + k;
        xoH[o] = h;
        xoL[o] = f2b(v - b2f(h));
    }
}

// ============== bn5 stats over relu(dout fp32) =============================
__global__ __launch_bounds__(256)
void stats5_kernel(const float* __restrict__ dout, float* __restrict__ sum5,
                   float* __restrict__ sq5)
{
    __shared__ float rs[256], rq[256];
    int c = blockIdx.x, tid = threadIdx.x;
    float s = 0.f, q = 0.f;
    for (int i = tid; i < 2048; i += 256) {
        float v = fmaxf(dout[(size_t)i * 256 + c], 0.f);
        s += v; q += v * v;
    }
    rs[tid] = s; rq[tid] = q; __syncthreads();
    for (int st = 128; st > 0; st >>= 1) {
        if (tid < st) { rs[tid] += rs[tid + st]; rq[tid] += rq[tid + st]; }
        __syncthreads();
    }
    if (tid == 0) { sum5[c] = rs[0]; sq5[c] = rq[0]; }
}

// ====== head: relu -> bn5 folded into mean -> fc -> log_softmax ============
__global__ __launch_bounds__(256)
void final_kernel(const float* __restrict__ dout, const float* __restrict__ A5,
                  const float* __restrict__ B5, const float* __restrict__ fcw,
                  const float* __restrict__ fcb, float* __restrict__ out)
{
    __shared__ float hbar[256];
    __shared__ float red[256];
    int b = blockIdx.x, tid = threadIdx.x;
    float s = 0.f;
#pragma unroll 4
    for (int px = 0; px < 16; px++)
        s += fmaxf(dout[((size_t)b * 16 + px) * 256 + tid], 0.f);
    hbar[tid] = fmaf(A5[tid], s * (1.f / 16.f), B5[tid]);
    __syncthreads();
    float logit = -1e30f;
    if (tid < 250) {
        float acc = fcb[tid];
        const float4* wr = (const float4*)(fcw + (size_t)tid * 256);
        const float4* hv = (const float4*)hbar;
#pragma unroll 4
        for (int i = 0; i < 64; i++) {
            float4 w4 = wr[i], h4 = hv[i];
            acc = fmaf(w4.x, h4.x, acc); acc = fmaf(w4.y, h4.y, acc);
            acc = fmaf(w4.z, h4.z, acc); acc = fmaf(w4.w, h4.w, acc);
        }
        logit = acc;
    }
    red[tid] = logit; __syncthreads();
    for (int st = 128; st > 0; st >>= 1) {
        if (tid < st) red[tid] = fmaxf(red[tid], red[tid + st]);
        __syncthreads();
    }
    float mx = red[0]; __syncthreads();
    float e = (tid < 250) ? expf(logit - mx) : 0.f;
    red[tid] = e; __syncthreads();
    for (int st = 128; st > 0; st >>= 1) {
        if (tid < st) red[tid] += red[tid + st];
        __syncthreads();
    }
    float lse = logf(red[0]) + mx;
    if (tid < 250) out[(size_t)b * 250 + tid] = logit - lse;
}

// ===========================================================================
extern "C" void kernel_launch(void* const* d_in, const int* in_sizes, int n_in,
                              void* d_out, int out_size, void* d_ws, size_t ws_size,
                              hipStream_t stream)
{
    const float* s_in = (const float*)d_in[0];
    const float* c1w = (const float*)d_in[1];  const float* c1b = (const float*)d_in[2];
    const float* g1  = (const float*)d_in[3];  const float* b1  = (const float*)d_in[4];
    const float* c2w = (const float*)d_in[5];  const float* c2b = (const float*)d_in[6];
    const float* g2  = (const float*)d_in[7];  const float* b2  = (const float*)d_in[8];
    const float* c3w = (const float*)d_in[9];  const float* c3b = (const float*)d_in[10];
    const float* g3  = (const float*)d_in[11]; const float* b3  = (const float*)d_in[12];
    const float* c4w = (const float*)d_in[13]; const float* c4b = (const float*)d_in[14];
    const float* g4  = (const float*)d_in[15]; const float* b4  = (const float*)d_in[16];
    const float* ofw = (const float*)d_in[17]; const float* ofb = (const float*)d_in[18];
    const float* dcw = (const float*)d_in[19];
    const float* g5  = (const float*)d_in[20]; const float* b5  = (const float*)d_in[21];
    const float* fcw = (const float*)d_in[22]; const float* fcb = (const float*)d_in[23];

    float* ws   = (float*)d_ws;
    float* stat = ws;                       // 2560
    float* ab   = ws + 2560;                // 2560
    float* zpad = ws + 5120;                // 64
    ushort* w2h = (ushort*)(ws + 5184);
    ushort* w2l = (ushort*)(ws + 42048);
    ushort* w3h = (ushort*)(ws + 78912);
    ushort* w3l = (ushort*)(ws + 226368);
    ushort* w4h = (ushort*)(ws + 373824);
    ushort* w4l = (ushort*)(ws + 668736);
    ushort* wdh = (ushort*)(ws + 963648);
    ushort* wdl = (ushort*)(ws + 1258560);
    ushort* poolH = (ushort*)(ws + 1553472);   // 8,388,608 u max
    ushort* poolL = (ushort*)(ws + 5747776);
    float*  conv32 = ws + 9942080;             // conv2/conv3 outs (16.7M f max)
    float*  c4parts = ws + 9942080;            // conv4 split-K parts (4 x 2,097,152)
    float*  c4out   = ws + 18330688;           // conv4 summed (2,097,152)
    float*  dparts  = ws + 20427840;           // dconv split-K parts (8 x 524,288)
    ushort* xoH  = (ushort*)(ws + 9942080);    // 4,718,592 u (after conv4 parts dead)
    ushort* xoL  = (ushort*)(ws + 12301376);
    float*  dout = ws + 14660672;              // 524,288 f
    float*  offb = ws + 15184960;              // 36,864 f

    hipMemsetAsync(stat, 0, 2048 * sizeof(float), stream);
    hipMemsetAsync(zpad, 0, 256, stream);

    // weight split-conversions
    wcvt_kernel<<<(128 * 64 * 9 + 255) / 256, 256, 0, stream>>>(c2w, w2h, w2l, 64, 1, 128 * 64 * 9);
    wcvt_kernel<<<(256 * 128 * 9 + 255) / 256, 256, 0, stream>>>(c3w, w3h, w3l, 128, 1, 256 * 128 * 9);
    wcvt_kernel<<<(256 * 256 * 9 + 255) / 256, 256, 0, stream>>>(c4w, w4h, w4l, 256, 1, 256 * 256 * 9);
    wcvt_kernel<<<(256 * 2304 + 255) / 256, 256, 0, stream>>>(dcw, wdh, wdl, 256, 0, 256 * 2304);

    // ---- stage 1: conv1 (recompute trick) -> hi/lo NHWC [B,32,32,64] ----
    conv1_kernel<1><<<dim3(512, 8), 256, 0, stream>>>(s_in, c1w, c1b, nullptr, nullptr,
                                                      stat, stat + 256, nullptr, nullptr);
    bn_finalize<<<1, 256, 0, stream>>>(stat, stat + 256, g1, b1, ab, ab + 256, 64,
                                       1.0f / (128.f * 64.f * 64.f));
    conv1_kernel<2><<<dim3(512, 8), 256, 0, stream>>>(s_in, c1w, c1b, poolH, poolL,
                                                      nullptr, nullptr, ab, ab + 256);

    // ---- stage 2: conv2 GEMM (M=131072, N=128, K=576), BN=128 ----
    gemm_kernel<576, 64, 32, 32, 128, true, true, true, 1, 128>
        <<<dim3(1024, 1), 256, 0, stream>>>(
        poolH, poolL, w2h, w2l, c2b, conv32, (const ushort*)zpad, stat + 512, stat + 768);
    bn_finalize<<<1, 256, 0, stream>>>(stat + 512, stat + 768, g2, b2, ab + 512, ab + 768,
                                       128, 1.0f / (128.f * 32.f * 32.f));
    bnpool_kernel<128, 32, 32><<<2048, 256, 0, stream>>>(conv32, ab + 512, ab + 768, poolH, poolL);

    // ---- stage 3: conv3 GEMM (M=32768, N=256, K=1152), BN=128 ----
    gemm_kernel<1152, 128, 16, 16, 256, true, true, true, 1, 128>
        <<<dim3(256, 2), 256, 0, stream>>>(
        poolH, poolL, w3h, w3l, c3b, conv32, (const ushort*)zpad, stat + 1024, stat + 1280);
    bn_finalize<<<1, 256, 0, stream>>>(stat + 1024, stat + 1280, g3, b3, ab + 1024, ab + 1280,
                                       256, 1.0f / (128.f * 16.f * 16.f));
    bnpool_kernel<256, 16, 16><<<1024, 256, 0, stream>>>(conv32, ab + 1024, ab + 1280, poolH, poolL);

    // ---- stage 4: conv4 GEMM (M=8192, N=256, K=2304), BN=128, split-K=4 ----
    gemm_kernel<2304, 256, 8, 8, 256, true, false, false, 4, 128>
        <<<dim3(64, 2, 4), 256, 0, stream>>>(
        poolH, poolL, w4h, w4l, nullptr, c4parts, (const ushort*)zpad, nullptr, nullptr);
    sumk_kernel<4, true, true><<<1024, 256, 0, stream>>>(
        c4parts, 2097152, c4b, c4out, stat + 1536, stat + 1792);
    bn_finalize<<<1, 256, 0, stream>>>(stat + 1536, stat + 1792, g4, b4, ab + 1536, ab + 1792,
                                       256, 1.0f / (128.f * 8.f * 8.f));
    bnpool_kernel<256, 8, 8><<<256, 256, 0, stream>>>(c4out, ab + 1536, ab + 1792, poolH, poolL);

    // ---- deformable conv (split-K=8) ----
    offconv_kernel<<<128, 256, 0, stream>>>(poolH, poolL, ofw, ofb, offb);
    sample_kernel<<<128, 256, 0, stream>>>(poolH, poolL, offb, xoH, xoL);
    gemm_kernel<2304, 2304, 1, 1, 256, false, false, false, 8, 64>
        <<<dim3(16, 4, 8), 256, 0, stream>>>(
        xoH, xoL, wdh, wdl, nullptr, dparts, (const ushort*)zpad, nullptr, nullptr);
    sumk_kernel<8, false, false><<<256, 256, 0, stream>>>(
        dparts, 524288, nullptr, dout, nullptr, nullptr);

    // ---- bn5 + head ----
    stats5_kernel<<<256, 256, 0, stream>>>(dout, stat + 2048, stat + 2304);
    bn_finalize<<<1, 256, 0, stream>>>(stat + 2048, stat + 2304, g5, b5, ab + 2048, ab + 2304,
                                       256, 1.0f / 2048.f);
    final_kernel<<<128, 256, 0, stream>>>(dout, ab + 2048, ab + 2304, fcw, fcb, (float*)d_out);
}